// Round 6
// baseline (242.800 us; speedup 1.0000x reference)
//
#include <hip/hip_runtime.h>
#include <math.h>

#define EMBED   1024
#define THREEC  3072
#define NH      16
#define HD      64
#define NFEAT   64      // R * M = 2 * 32
#define RN      2
#define MM_     32
#define B_      2
#define T_      4096
#define L_      64      // chunk length
#define NC_     64      // T_ / L_
#define BH_     32      // B_ * NH

typedef __attribute__((ext_vector_type(8))) short bf16x8;
typedef __attribute__((ext_vector_type(4))) float f32x4;

__device__ __forceinline__ float bf2f(short s) {
    unsigned u = ((unsigned)(unsigned short)s) << 16;
    return __builtin_bit_cast(float, u);
}
__device__ __forceinline__ short f2bf(float f) {
    unsigned u = __builtin_bit_cast(unsigned, f);
    u += 0x7fff + ((u >> 16) & 1);
    return (short)(u >> 16);
}
__device__ __forceinline__ void gload16(const short* g, short* l) {
    __builtin_amdgcn_global_load_lds(
        (const __attribute__((address_space(1))) void*)g,
        (__attribute__((address_space(3))) void*)l, 16, 0, 0);
}

// ---------------------------------------------------------------------------
// f32 -> bf16 cast, 8 elems/thread
// ---------------------------------------------------------------------------
__global__ __launch_bounds__(256) void cast_kernel(
    const float* __restrict__ in, short* __restrict__ out, int n8)
{
    int i = blockIdx.x * 256 + threadIdx.x;
    if (i >= n8) return;
    const float4* p = (const float4*)in + (size_t)i * 2;
    float4 a = p[0], b = p[1];
    bf16x8 o = { f2bf(a.x), f2bf(a.y), f2bf(a.z), f2bf(a.w),
                 f2bf(b.x), f2bf(b.y), f2bf(b.z), f2bf(b.w) };
    *((bf16x8*)out + i) = o;
}

// ---------------------------------------------------------------------------
// omega [R,H,D,M] fp32 -> omgT[h][f=r*32+m][d] bf16 hi/lo split
// ---------------------------------------------------------------------------
__global__ __launch_bounds__(256) void omega_prep(
    const float* __restrict__ omega, short* __restrict__ hi, short* __restrict__ lo)
{
    int i = blockIdx.x * 256 + threadIdx.x;   // over H*F*D = 65536
    if (i >= NH * NFEAT * HD) return;
    int d = i & 63;
    int f = (i >> 6) & 63;
    int h = i >> 12;
    int r = f >> 5, m = f & 31;
    float w = omega[(((size_t)(r * NH + h) * HD + d) * MM_) + m];
    short a = f2bf(w);
    hi[i] = a;
    lo[i] = f2bf(w - bf2f(a));
}

// ---------------------------------------------------------------------------
// 8-phase 256x256 bf16 MFMA GEMM (m201-style schedule, plain HIP).
// BK=64 split as 2 K-halves (kh) of 32; 2 LDS dbufs; 512 thr = 8 waves (2x4),
// per-wave output 128x64 (acc[8][4]).
// Per phase: {ds_read 8 A-frags or 4 B-frags | stage 1 half-tile (2 gload16)
//   | barrier | lgkmcnt(0)+sched_barrier | setprio(1) 16 MFMA setprio(0)
//   | [vmcnt(6) at ph4/ph8] | barrier}.
// LDS region (buf,kh) staged exactly one phase after its last read (WAR via
// phase barrier); vmcnt(6) at ph4/ph8 lands the K-tile needed next (RAW),
// leaving 3 half-tiles in flight.
// Swizzle: granule g ^= (row>>1)&3 on both stage-source and ds_read (2-way max).
// C[m,n] = sum_k A[m*K+k]*W[n*K+k] + bias[n], bf16 out.
// Requires M%256==0, N%256==0, K%128==0.
// ---------------------------------------------------------------------------
__global__ __launch_bounds__(512, 2) void gemm_8ph(
    const short* __restrict__ Ag,     // [M][K] bf16
    const short* __restrict__ Wg,     // [N][K] bf16
    const float* __restrict__ bias,   // [N]
    short* __restrict__ Cb,           // [M][N] bf16
    int M, int N, int K)
{
    __shared__ short LDS[65536];      // 128 KiB: A regions [0..32767], B [32768..]

    const int tid  = threadIdx.x;
    const int nbn  = N >> 8;
    const int nwg  = gridDim.x;
    const int cpx  = nwg >> 3;                    // grid % 8 == 0
    const int bid  = blockIdx.x;
    const int swz  = (bid & 7) * cpx + (bid >> 3);
    const int bm   = (swz / nbn) << 8;
    const int bn   = (swz % nbn) << 8;

    const int lane = tid & 63;
    const int wid  = tid >> 6;
    const int wm   = wid >> 2;        // 0..1 (row half)
    const int wn   = wid & 3;         // 0..3 (col quarter)
    const int lr   = lane & 15;
    const int G    = lane >> 4;       // k-granule 0..3

    const int r2   = tid >> 2;        // staging row 0..127
    const int gsw  = (tid & 3) ^ ((r2 >> 1) & 3); // pre-swizzled source granule
    const int KT   = K >> 6;          // BK=64 tiles
    const int KT2  = KT >> 1;

    f32x4  acc[8][4] = {};
    bf16x8 afk0[8], afk1[8], bfk0[4], bfk1[4];
    {   // zero frag sets used by the (skipped) first phantom MFMA group
        bf16x8 z = {0,0,0,0,0,0,0,0};
        #pragma unroll
        for (int i = 0; i < 8; ++i) afk1[i] = z;
        #pragma unroll
        for (int i = 0; i < 4; ++i) bfk1[i] = z;
    }

    // region base (shorts): A: (buf*2+kh)*8192 ; B: 32768 + (buf*2+kh)*8192
#define ST_A(buf, kh, kt) { \
        short* ldst = &LDS[((buf) * 2 + (kh)) * 8192]; \
        gload16(&Ag[(size_t)(bm + r2) * K + (kt) * 64 + (kh) * 32 + gsw * 8], \
                ldst + tid * 8); \
        gload16(&Ag[(size_t)(bm + 128 + r2) * K + (kt) * 64 + (kh) * 32 + gsw * 8], \
                ldst + 4096 + tid * 8); }
#define ST_B(buf, kh, kt) { \
        short* ldst = &LDS[32768 + ((buf) * 2 + (kh)) * 8192]; \
        gload16(&Wg[(size_t)(bn + r2) * K + (kt) * 64 + (kh) * 32 + gsw * 8], \
                ldst + tid * 8); \
        gload16(&Wg[(size_t)(bn + 128 + r2) * K + (kt) * 64 + (kh) * 32 + gsw * 8], \
                ldst + 4096 + tid * 8); }
#define RD_A(dst, buf, kh) { \
        const short* lsrc = &LDS[((buf) * 2 + (kh)) * 8192]; \
        _Pragma("unroll") \
        for (int fr = 0; fr < 8; ++fr) { \
            const int row = wm * 128 + fr * 16 + lr; \
            dst[fr] = *(const bf16x8*)&lsrc[row * 32 + ((G ^ ((row >> 1) & 3)) << 3)]; } }
#define RD_B(dst, buf, kh) { \
        const short* lsrc = &LDS[32768 + ((buf) * 2 + (kh)) * 8192]; \
        _Pragma("unroll") \
        for (int fc = 0; fc < 4; ++fc) { \
            const int row = wn * 64 + fc * 16 + lr; \
            dst[fc] = *(const bf16x8*)&lsrc[row * 32 + ((G ^ ((row >> 1) & 3)) << 3)]; } }
#define MM(frh, AF, BF) \
        _Pragma("unroll") \
        for (int fr = 0; fr < 4; ++fr) \
            _Pragma("unroll") \
            for (int fc = 0; fc < 4; ++fc) \
                acc[(frh) * 4 + fr][fc] = __builtin_amdgcn_mfma_f32_16x16x32_bf16( \
                    AF[(frh) * 4 + fr], BF[fc], acc[(frh) * 4 + fr][fc], 0, 0, 0);
#define BAR   __builtin_amdgcn_s_barrier()
#define LGKM0 { asm volatile("s_waitcnt lgkmcnt(0)" ::: "memory"); \
                __builtin_amdgcn_sched_barrier(0); }
#define PRIO1 __builtin_amdgcn_s_setprio(1)
#define PRIO0 __builtin_amdgcn_s_setprio(0)

    // Prologue: stream-stage kt0 {A0,B0,A1,B1}, kt1 {A0,B0,A1}; gate kt0.
    ST_A(0, 0, 0); ST_B(0, 0, 0); ST_A(0, 1, 0); ST_B(0, 1, 0);
    ST_A(1, 0, 1); ST_B(1, 0, 1); ST_A(1, 1, 1);
    asm volatile("s_waitcnt vmcnt(6)" ::: "memory");
    BAR;

    for (int t = 0; t < KT2; ++t) {
        const int ktA = 2 * t;
        const int ktB = 2 * t + 1;
        // ph1: read A(buf0,k0); stage ktB:B1; MFMA prev (frh1,k1)
        RD_A(afk0, 0, 0);
        ST_B(1, 1, ktB);
        BAR; LGKM0;
        PRIO1; MM(1, afk1, bfk1); PRIO0;
        BAR;
        // ph2
        RD_B(bfk0, 0, 0);
        if (ktA + 2 < KT) ST_A(0, 0, ktA + 2);
        BAR; LGKM0;
        PRIO1; MM(0, afk0, bfk0); PRIO0;
        BAR;
        // ph3
        RD_A(afk1, 0, 1);
        if (ktA + 2 < KT) ST_B(0, 0, ktA + 2);
        BAR; LGKM0;
        PRIO1; MM(1, afk0, bfk0); PRIO0;
        BAR;
        // ph4  (gate for ktB's reads in ph5-8)
        RD_B(bfk1, 0, 1);
        if (ktA + 2 < KT) ST_A(0, 1, ktA + 2);
        BAR; LGKM0;
        PRIO1; MM(0, afk1, bfk1); PRIO0;
        if (ktA + 2 < KT) { asm volatile("s_waitcnt vmcnt(6)" ::: "memory"); }
        else              { asm volatile("s_waitcnt vmcnt(0)" ::: "memory"); }
        BAR;
        // ph5
        RD_A(afk0, 1, 0);
        if (ktA + 2 < KT) ST_B(0, 1, ktA + 2);
        BAR; LGKM0;
        PRIO1; MM(1, afk1, bfk1); PRIO0;       // ktA (frh1,k1)
        BAR;
        // ph6
        RD_B(bfk0, 1, 0);
        if (ktB + 2 < KT) ST_A(1, 0, ktB + 2);
        BAR; LGKM0;
        PRIO1; MM(0, afk0, bfk0); PRIO0;
        BAR;
        // ph7
        RD_A(afk1, 1, 1);
        if (ktB + 2 < KT) ST_B(1, 0, ktB + 2);
        BAR; LGKM0;
        PRIO1; MM(1, afk0, bfk0); PRIO0;
        BAR;
        // ph8  (gate for next iter's ph1-4 reads)
        RD_B(bfk1, 1, 1);
        if (ktB + 2 < KT) ST_A(1, 1, ktB + 2);
        BAR; LGKM0;
        PRIO1; MM(0, afk1, bfk1); PRIO0;
        if (ktB + 2 < KT) { asm volatile("s_waitcnt vmcnt(6)" ::: "memory"); }
        else              { asm volatile("s_waitcnt vmcnt(0)" ::: "memory"); }
        BAR;
    }
    // final deferred group: kt(KT-1) (frh1,k1)
    MM(1, afk1, bfk1);

#undef ST_A
#undef ST_B
#undef RD_A
#undef RD_B
#undef MM

    // Epilogue: 2-pass LDS transpose -> coalesced bf16x8 row stores.
    float bv[4];
    #pragma unroll
    for (int fc = 0; fc < 4; ++fc)
        bv[fc] = bias[bn + wn * 64 + fc * 16 + lr];

    short* E = (short*)LDS;           // [128][264]
    #pragma unroll 1
    for (int pass = 0; pass < 2; ++pass) {
        __syncthreads();
        if (wm == pass) {
            #pragma unroll
            for (int fr = 0; fr < 8; ++fr)
                #pragma unroll
                for (int fc = 0; fc < 4; ++fc) {
                    const int col = wn * 64 + fc * 16 + lr;
                    #pragma unroll
                    for (int j = 0; j < 4; ++j) {
                        const int rl = fr * 16 + G * 4 + j;
                        E[rl * 264 + col] = f2bf(acc[fr][fc][j] + bv[fc]);
                    }
                }
        }
        __syncthreads();
        #pragma unroll
        for (int i = 0; i < 8; ++i) {
            const int idx = i * 512 + tid;        // 0..4095
            const int rl  = idx >> 5;
            const int c8  = idx & 31;
            bf16x8 v = *(const bf16x8*)&E[rl * 264 + c8 * 8];
            *(bf16x8*)&Cb[(size_t)(bm + pass * 128 + rl) * N + bn + c8 * 8] = v;
        }
    }
}

// ---------------------------------------------------------------------------
// bf16 MFMA GEMM (m97 structure) — used for the output projection
// ---------------------------------------------------------------------------
template<int OUTBF>
__global__ __launch_bounds__(256) void gemm_bf16(
    const short* __restrict__ A,      // [M][K] bf16
    const short* __restrict__ W,      // [N][K] bf16
    const float* __restrict__ bias,   // [N]
    float* __restrict__ Cf, short* __restrict__ Cb,
    int M, int N, int K)
{
    __shared__ short lA[2][128 * 32];
    __shared__ short lB[2][128 * 32];
    const int tid  = threadIdx.x;
    const int bm   = blockIdx.y * 128;
    const int bn   = blockIdx.x * 128;
    const int lane = tid & 63;
    const int wave = tid >> 6;
    const int row0 = (wave >> 1) * 64;
    const int col0 = (wave & 1) * 64;
    const int lr   = lane & 15;
    const int kg8  = (lane >> 4) * 8;

    f32x4 acc[4][4] = {};

#define STAGE(buf, k0)                                                        \
    {                                                                         \
        _Pragma("unroll")                                                     \
        for (int i = 0; i < 2; ++i) {                                         \
            int idx = i * 256 + tid;                                          \
            int row = idx >> 2, kq = (idx & 3) * 8;                           \
            gload16(&A[(size_t)(bm + row) * K + (k0) + kq], &lA[buf][idx * 8]); \
            gload16(&W[(size_t)(bn + row) * K + (k0) + kq], &lB[buf][idx * 8]); \
        }                                                                     \
    }

    const int KT = K >> 5;
    STAGE(0, 0);
    __syncthreads();
    int cur = 0;
    for (int kt = 0; kt < KT; ++kt) {
        if (kt + 1 < KT) STAGE(cur ^ 1, (kt + 1) * 32);
        const short* As = lA[cur];
        const short* Bs = lB[cur];
        bf16x8 af[4], bfr[4];
        #pragma unroll
        for (int m = 0; m < 4; ++m)
            af[m] = *(const bf16x8*)&As[(row0 + m * 16 + lr) * 32 + kg8];
        #pragma unroll
        for (int n = 0; n < 4; ++n)
            bfr[n] = *(const bf16x8*)&Bs[(col0 + n * 16 + lr) * 32 + kg8];
        #pragma unroll
        for (int m = 0; m < 4; ++m)
            #pragma unroll
            for (int n = 0; n < 4; ++n)
                acc[m][n] = __builtin_amdgcn_mfma_f32_16x16x32_bf16(
                    af[m], bfr[n], acc[m][n], 0, 0, 0);
        __syncthreads();
        cur ^= 1;
    }
#undef STAGE

    #pragma unroll
    for (int n = 0; n < 4; ++n) {
        const int col = bn + col0 + n * 16 + (lane & 15);
        const float bvv = bias[col];
        #pragma unroll
        for (int m = 0; m < 4; ++m) {
            const int rbase = bm + row0 + m * 16 + (lane >> 4) * 4;
            #pragma unroll
            for (int j = 0; j < 4; ++j) {
                const float v = acc[m][n][j] + bvv;
                if (OUTBF) Cb[(size_t)(rbase + j) * N + col] = f2bf(v);
                else       Cf[(size_t)(rbase + j) * N + col] = v;
            }
        }
    }
}

// ---------------------------------------------------------------------------
// Feature map (MFMA), writing bf16 qf/kf.
// ---------------------------------------------------------------------------
__global__ __launch_bounds__(256) void features_mfma(
    const short* __restrict__ qkvb,       // [B, T, 3C] bf16
    const short* __restrict__ omgH,       // [H][64f][64d] bf16 (hi)
    const short* __restrict__ omgL,       // [H][64f][64d] bf16 (lo)
    const float* __restrict__ qn,
    const float* __restrict__ qw,
    short* __restrict__ qf,               // [BH, T, 64] bf16
    short* __restrict__ kf)
{
    __shared__ short zq[64][72];
    __shared__ short zk[64][72];
    __shared__ short omh[64][72];
    __shared__ short oml[64][72];
    __shared__ float invn[2][64];

    const int tid = threadIdx.x;
    const int bh  = blockIdx.x >> 6;      // 0..31
    const int tb  = blockIdx.x & 63;      // 0..63
    const int b   = bh >> 4, h = bh & 15;
    const int t0  = tb * 64;

    {
        const int row = tid >> 2;
        const int c0  = (tid & 3) * 16;
        const size_t zbase = ((size_t)(b * T_ + t0 + row)) * THREEC + h * HD + c0;
        const size_t obase = ((size_t)h * NFEAT + row) * HD + c0;
        *(bf16x8*)&zq[row][c0]      = *(const bf16x8*)&qkvb[zbase];
        *(bf16x8*)&zq[row][c0 + 8]  = *(const bf16x8*)&qkvb[zbase + 8];
        *(bf16x8*)&zk[row][c0]      = *(const bf16x8*)&qkvb[zbase + EMBED];
        *(bf16x8*)&zk[row][c0 + 8]  = *(const bf16x8*)&qkvb[zbase + EMBED + 8];
        *(bf16x8*)&omh[row][c0]     = *(const bf16x8*)&omgH[obase];
        *(bf16x8*)&omh[row][c0 + 8] = *(const bf16x8*)&omgH[obase + 8];
        *(bf16x8*)&oml[row][c0]     = *(const bf16x8*)&omgL[obase];
        *(bf16x8*)&oml[row][c0 + 8] = *(const bf16x8*)&omgL[obase + 8];
    }
    __syncthreads();

    {
        const int t = tid >> 2;
        const int q = tid & 3;
        #pragma unroll
        for (int p = 0; p < 2; ++p) {
            const short* Z = p ? &zk[t][q * 16] : &zq[t][q * 16];
            float ss = 0.0f;
            #pragma unroll
            for (int j = 0; j < 16; ++j) { float v = bf2f(Z[j]); ss += v * v; }
            ss += __shfl_xor(ss, 1, 64);
            ss += __shfl_xor(ss, 2, 64);
            if (q == 0) invn[p][t] = 1.0f / fmaxf(sqrtf(ss), 1e-12f);
        }
    }
    __syncthreads();

    const int wave = tid >> 6;
    const int lane = tid & 63;
    const int p    = wave >> 1;           // 0 = q, 1 = k
    const int half = wave & 1;            // token half
    const short (*Z)[72] = p ? zk : zq;

    const float s0 = qn[0], s1 = qn[1];
    const float sq2s0 = sqrtf(2.0f * fmaxf(s0, 0.0f));
    const float sq2s1 = sqrtf(2.0f * fmaxf(s1, 0.0f));
    const float sc0 = sqrtf(fmaxf(qw[0], 0.0f)) * (1.0f / 32.0f);
    const float sc1 = sqrtf(fmaxf(qw[1], 0.0f)) * (1.0f / 32.0f);

    const int lr  = lane & 15;
    const int kg8 = (lane >> 4) * 8;

    f32x4 acc[2][4] = {};
    #pragma unroll
    for (int kk = 0; kk < 2; ++kk) {
        bf16x8 a[2], bh8[4], bl8[4];
        #pragma unroll
        for (int m = 0; m < 2; ++m)
            a[m] = *(const bf16x8*)&Z[half * 32 + m * 16 + lr][kk * 32 + kg8];
        #pragma unroll
        for (int n = 0; n < 4; ++n) {
            bh8[n] = *(const bf16x8*)&omh[n * 16 + lr][kk * 32 + kg8];
            bl8[n] = *(const bf16x8*)&oml[n * 16 + lr][kk * 32 + kg8];
        }
        #pragma unroll
        for (int m = 0; m < 2; ++m)
            #pragma unroll
            for (int n = 0; n < 4; ++n) {
                acc[m][n] = __builtin_amdgcn_mfma_f32_16x16x32_bf16(
                    a[m], bh8[n], acc[m][n], 0, 0, 0);
                acc[m][n] = __builtin_amdgcn_mfma_f32_16x16x32_bf16(
                    a[m], bl8[n], acc[m][n], 0, 0, 0);
            }
    }

    short* dstbase = (p ? kf : qf) + ((size_t)bh * T_ + t0) * NFEAT;
    #pragma unroll
    for (int n = 0; n < 4; ++n) {
        const int f = n * 16 + (lane & 15);
        const float s_r   = (n < 2) ? s0 : s1;
        const float sq2s  = (n < 2) ? sq2s0 : sq2s1;
        const float scale = (n < 2) ? sc0 : sc1;
        #pragma unroll
        for (int m = 0; m < 2; ++m) {
            const int tb4 = half * 32 + m * 16 + (lane >> 4) * 4;
            #pragma unroll
            for (int j = 0; j < 4; ++j) {
                const int t = tb4 + j;
                const float proj = acc[m][n][j] * invn[p][t];
                const float arg = fminf(fmaxf(proj * sq2s - s_r, -20.0f), 20.0f);
                const float val = proj * proj * __expf(arg) * scale;
                dstbase[(size_t)t * NFEAT + f] = f2bf(val);
            }
        }
    }
}

// ---------------------------------------------------------------------------
// Per-chunk KV sums. Writes cKV TRANSPOSED: [chunk][d][f] = S[f][d].
// ---------------------------------------------------------------------------
__global__ __launch_bounds__(256) void chunk_sums(
    const short* __restrict__ kf,         // bf16
    const short* __restrict__ qkvb,
    float* __restrict__ cKV,              // [BH*NC, 64d, 64f]
    float* __restrict__ cK)               // [BH*NC, 64]
{
    __shared__ float kfs[64][64];
    __shared__ float vs[64][64];
    float (*st)[65] = (float(*)[65])kfs;  // reuse after compute

    const int tid = threadIdx.x;
    const int chunk = blockIdx.x;
    const int bh = chunk >> 6, c = chunk & 63;
    const int b = bh >> 4, h = bh & 15;
    const int t0 = c * L_;

    {
        const int row = tid >> 2;
        const int c0  = (tid & 3) * 16;
        const short* krow = kf + ((size_t)bh * T_ + t0 + row) * NFEAT;
        const short* vrow = qkvb + ((size_t)(b * T_ + t0 + row)) * THREEC + 2 * EMBED + h * HD;
        bf16x8 k0 = *(const bf16x8*)&krow[c0], k1 = *(const bf16x8*)&krow[c0 + 8];
        bf16x8 v0 = *(const bf16x8*)&vrow[c0], v1 = *(const bf16x8*)&vrow[c0 + 8];
        #pragma unroll
        for (int j = 0; j < 8; ++j) {
            kfs[row][c0 + j]     = bf2f(k0[j]);
            kfs[row][c0 + 8 + j] = bf2f(k1[j]);
            vs[row][c0 + j]      = bf2f(v0[j]);
            vs[row][c0 + 8 + j]  = bf2f(v1[j]);
        }
    }
    __syncthreads();

    const int f  = tid >> 2;
    const int d0 = (tid & 3) * 16;
    float acc[16] = {};
    float ks = 0.0f;
    for (int t = 0; t < L_; ++t) {
        const float kft = kfs[t][f];
        ks += kft;
        #pragma unroll
        for (int j = 0; j < 16; ++j) acc[j] += kft * vs[t][d0 + j];
    }
    if ((tid & 3) == 0) cK[(size_t)chunk * NFEAT + f] = ks;
    __syncthreads();   // done reading kfs/vs

    #pragma unroll
    for (int j = 0; j < 16; ++j) st[f][d0 + j] = acc[j];
    __syncthreads();

    {
        const int d  = tid >> 2;
        const int f0 = (tid & 3) * 16;
        float* dst = cKV + (size_t)chunk * (NFEAT * HD) + tid * 16;
        #pragma unroll
        for (int q = 0; q < 4; ++q) {
            float4 o;
            o.x = st[f0 + q * 4 + 0][d];
            o.y = st[f0 + q * 4 + 1][d];
            o.z = st[f0 + q * 4 + 2][d];
            o.w = st[f0 + q * 4 + 3][d];
            *(float4*)&dst[q * 4] = o;
        }
    }
}

// ---------------------------------------------------------------------------
// Exclusive prefix over chunks. grid: BH_*4 blocks; depth-2 prefetch.
// ---------------------------------------------------------------------------
__global__ __launch_bounds__(256) void prefix_scan(
    float* __restrict__ cKV, float* __restrict__ cK)
{
    const int bh  = blockIdx.x >> 2;
    const int sl  = blockIdx.x & 3;
    const int tid = threadIdx.x;
    float4* base = (float4*)(cKV + (size_t)bh * NC_ * (NFEAT * HD) + sl * 1024) + tid;
    float4 n0 = base[0];
    float4 n1 = base[1024];
    float4 pref; pref.x = pref.y = pref.z = pref.w = 0.0f;
    for (int c = 0; c < NC_; ++c) {
        float4 cur = n0;
        n0 = n1;
        if (c + 2 < NC_) n1 = base[(size_t)(c + 2) * 1024];
        else { n1.x = n1.y = n1.z = n1.w = 0.0f; }
        base[(size_t)c * 1024] = pref;
        pref.x += cur.x; pref.y += cur.y; pref.z += cur.z; pref.w += cur.w;
    }
    if (sl == 0 && tid < 64) {
        float* kb = cK + (size_t)bh * NC_ * NFEAT + tid;
        float m0 = kb[0];
        float m1 = kb[64];
        float p = 0.0f;
        for (int c = 0; c < NC_; ++c) {
            float cu = m0;
            m0 = m1;
            m1 = (c + 2 < NC_) ? kb[(size_t)(c + 2) * 64] : 0.0f;
            kb[(size_t)c * 64] = p;
            p += cu;
        }
    }
}

// ---------------------------------------------------------------------------
// Intra-chunk causal attention via MFMA. 4 waves, each owns a 16-row band.
// ---------------------------------------------------------------------------
__global__ __launch_bounds__(256) void intra_mfma(
    const short* __restrict__ qf,         // [BH,T,64] bf16
    const short* __restrict__ kf,
    const short* __restrict__ qkvb,       // v region (bf16)
    const float* __restrict__ cKV,        // [chunk][d][f] prefix fp32
    const float* __restrict__ cK,         // [chunk][f] prefix fp32
    short* __restrict__ attnb)            // [B*T, EMBED] bf16
{
    __shared__ short Qs[64][72];
    __shared__ short Ks[64][72];
    __shared__ short Vt[64][72];          // V^T: [d][t]
    __shared__ short Pp[64][72];          // KVp^T: [d][f]
    __shared__ short At[64][72];          // masked A: [t][s]
    __shared__ float rs_l[64], qkp_l[64], cKp[64];

    const int tid = threadIdx.x;
    const int chunk = blockIdx.x;
    const int bh = chunk >> 6, c = chunk & 63;
    const int b = bh >> 4, h = bh & 15;
    const int t0 = c * L_;

    {
        const int row = tid >> 2;
        const int c0  = (tid & 3) * 16;
        const short* qrow = qf + ((size_t)bh * T_ + t0 + row) * NFEAT;
        const short* krow = kf + ((size_t)bh * T_ + t0 + row) * NFEAT;
        const short* vrow = qkvb + ((size_t)(b * T_ + t0 + row)) * THREEC + 2 * EMBED + h * HD;
        *(bf16x8*)&Qs[row][c0]     = *(const bf16x8*)&qrow[c0];
        *(bf16x8*)&Qs[row][c0 + 8] = *(const bf16x8*)&qrow[c0 + 8];
        *(bf16x8*)&Ks[row][c0]     = *(const bf16x8*)&krow[c0];
        *(bf16x8*)&Ks[row][c0 + 8] = *(const bf16x8*)&krow[c0 + 8];
        bf16x8 v0 = *(const bf16x8*)&vrow[c0], v1 = *(const bf16x8*)&vrow[c0 + 8];
        #pragma unroll
        for (int j = 0; j < 8; ++j) {
            Vt[c0 + j][row]     = v0[j];
            Vt[c0 + 8 + j][row] = v1[j];
        }
        const float* pbase = cKV + (size_t)chunk * (NFEAT * HD) + tid * 16;
        float4 p0 = *(const float4*)&pbase[0],  p1 = *(const float4*)&pbase[4];
        float4 p2 = *(const float4*)&pbase[8],  p3 = *(const float4*)&pbase[12];
        bf16x8 o0 = { f2bf(p0.x), f2bf(p0.y), f2bf(p0.z), f2bf(p0.w),
                      f2bf(p1.x), f2bf(p1.y), f2bf(p1.z), f2bf(p1.w) };
        bf16x8 o1 = { f2bf(p2.x), f2bf(p2.y), f2bf(p2.z), f2bf(p2.w),
                      f2bf(p3.x), f2bf(p3.y), f2bf(p3.z), f2bf(p3.w) };
        *(bf16x8*)&Pp[row][c0]     = o0;
        *(bf16x8*)&Pp[row][c0 + 8] = o1;
        if (tid < 64) cKp[tid] = cK[(size_t)chunk * NFEAT + tid];
    }
    __syncthreads();

    const int wave = tid >> 6;
    const int lane = tid & 63;
    const int lr   = lane & 15;
    const int kg   = (lane >> 4) * 8;
    const int r0   = wave * 16;

    bf16x8 aq[2];
    aq[0] = *(const bf16x8*)&Qs[r0 + lr][kg];
    aq[1] = *(const bf16x8*)&Qs[r0 + lr][32 + kg];
    f32x4 accA[4] = {};
    #pragma unroll
    for (int n = 0; n < 4; ++n) {
        accA[n] = __builtin_amdgcn_mfma_f32_16x16x32_bf16(
            aq[0], *(const bf16x8*)&Ks[n * 16 + lr][kg], accA[n], 0, 0, 0);
        accA[n] = __builtin_amdgcn_mfma_f32_16x16x32_bf16(
            aq[1], *(const bf16x8*)&Ks[n * 16 + lr][32 + kg], accA[n], 0, 0, 0);
    }
    float rsum[4] = {0.0f, 0.0f, 0.0f, 0.0f};
    #pragma unroll
    for (int n = 0; n < 4; ++n) {
        const int s = n * 16 + lr;
        #pragma unroll
        for (int j = 0; j < 4; ++j) {
            const int t = r0 + (lane >> 4) * 4 + j;
            const float a = (s <= t) ? accA[n][j] : 0.0f;
            rsum[j] += a;
            At[t][s] = f2bf(a);
        }
    }
    #pragma unroll
    for (int j = 0; j < 4; ++j) {
        rsum[j] += __shfl_xor(rsum[j], 1, 64);
        rsum[j] += __shfl_xor(rsum[j], 2, 64);
        rsum[j] += __shfl_xor(rsum[j], 4, 64);
        rsum[j] += __shfl_xor(rsum[j], 8, 64);
    }
    if (lr == 0) {
        #pragma unroll
        for (int j = 0; j < 4; ++j) rs_l[r0 + (lane >> 4) * 4 + j] = rsum[j];
    }

    {
        const int t  = tid >> 2;
        const int fq = (tid & 3) * 16;
        float s = 0.0f;
        #pragma unroll
        for (int j = 0; j < 16; ++j) s += bf2f(Qs[t][fq + j]) * cKp[fq + j];
        s += __shfl_xor(s, 1, 64);
        s += __shfl_xor(s, 2, 64);
        if ((tid & 3) == 0) qkp_l[t] = s;
    }
    __syncthreads();

    bf16x8 aa[2];
    aa[0] = *(const bf16x8*)&At[r0 + lr][kg];
    aa[1] = *(const bf16x8*)&At[r0 + lr][32 + kg];
    f32x4 acc[4] = {};
    #pragma unroll
    for (int n = 0; n < 4; ++n) {
        acc[n] = __builtin_amdgcn_mfma_f32_16x16x32_bf16(
            aa[0], *(const bf16x8*)&Vt[n * 16 + lr][kg], acc[n], 0, 0, 0);
        acc[n] = __builtin_amdgcn_mfma_f32_16x16x32_bf16(
            aa[1], *(const bf16x8*)&Vt[n * 16 + lr][32 + kg], acc[n], 0, 0, 0);
        acc[n] = __builtin_amdgcn_mfma_f32_16x16x32_bf16(
            aq[0], *(const bf16x8*)&Pp[n * 16 + lr][kg], acc[n], 0, 0, 0);
        acc[n] = __builtin_amdgcn_mfma_f32_16x16x32_bf16(
            aq[1], *(const bf16x8*)&Pp[n * 16 + lr][32 + kg], acc[n], 0, 0, 0);
    }

    float inv[4];
    #pragma unroll
    for (int j = 0; j < 4; ++j) {
        const int t = r0 + (lane >> 4) * 4 + j;
        inv[j] = 1.0f / fmaxf(rs_l[t] + qkp_l[t], 1e-6f);
    }
    #pragma unroll
    for (int n = 0; n < 4; ++n) {
        const int d = n * 16 + lr;
        #pragma unroll
        for (int j = 0; j < 4; ++j) {
            const int t = r0 + (lane >> 4) * 4 + j;
            attnb[((size_t)(b * T_ + t0 + t)) * EMBED + h * HD + d] =
                f2bf(acc[n][j] * inv[j]);
        }
    }
}

// ---------------------------------------------------------------------------
extern "C" void kernel_launch(void* const* d_in, const int* in_sizes, int n_in,
                              void* d_out, int out_size, void* d_ws, size_t ws_size,
                              hipStream_t stream)
{
    const float* x     = (const float*)d_in[0];
    const float* w_qkv = (const float*)d_in[1];
    const float* b_qkv = (const float*)d_in[2];
    const float* w_out = (const float*)d_in[3];
    const float* b_out = (const float*)d_in[4];
    const float* omega = (const float*)d_in[5];
    const float* qn    = (const float*)d_in[6];
    const float* qw    = (const float*)d_in[7];
    float* out = (float*)d_out;

    // workspace layout (shorts first, then floats)
    short* xb    = (short*)d_ws;               //  8,388,608
    short* wqb   = xb    + 8388608;            //  3,145,728
    short* wob   = wqb   + 3145728;            //  1,048,576
    short* qkvb  = wob   + 1048576;            // 25,165,824
    short* attnb = qkvb  + 25165824;           //  8,388,608
    short* omgH  = attnb + 8388608;            //     65,536
    short* omgL  = omgH  + 65536;              //     65,536
    short* qfb   = omgL  + 65536;              //  8,388,608
    short* kfb   = qfb   + 8388608;            //  8,388,608
    float* cKV   = (float*)(kfb + 8388608);    //  8,388,608 floats
    float* cK    = cKV + 8388608;              //    131,072 floats

    const int M = B_ * T_;   // 8192

    cast_kernel<<<dim3(8388608 / 8 / 256), 256, 0, stream>>>(x, xb, 8388608 / 8);
    cast_kernel<<<dim3(3145728 / 8 / 256), 256, 0, stream>>>(w_qkv, wqb, 3145728 / 8);
    cast_kernel<<<dim3(1048576 / 8 / 256), 256, 0, stream>>>(w_out, wob, 1048576 / 8);
    omega_prep<<<dim3(256), 256, 0, stream>>>(omega, omgH, omgL);

    // 1. qkv = x @ w_qkv^T + b_qkv  (bf16 out) — 8-phase 256^2 kernel
    gemm_8ph<<<dim3((M / 256) * (THREEC / 256)), 512, 0, stream>>>(
        xb, wqb, b_qkv, qkvb, M, THREEC, EMBED);
    // 2. features (MFMA, bf16 out)
    features_mfma<<<dim3(BH_ * (T_ / 64)), 256, 0, stream>>>(
        qkvb, omgH, omgL, qn, qw, qfb, kfb);
    // 3. per-chunk KV sums (transposed cKV)
    chunk_sums<<<dim3(BH_ * NC_), 256, 0, stream>>>(kfb, qkvb, cKV, cK);
    // 4. exclusive prefix over chunks
    prefix_scan<<<dim3(BH_ * 4), 256, 0, stream>>>(cKV, cK);
    // 5. intra-chunk attention (MFMA) -> bf16 attn [B*T, C]
    intra_mfma<<<dim3(BH_ * NC_), 256, 0, stream>>>(qfb, kfb, qkvb, cKV, cK, attnb);
    // 6. out = attn @ w_out^T + b_out (fp32 out)
    gemm_bf16<0><<<dim3(EMBED / 128, M / 128), 256, 0, stream>>>(
        attnb, wob, b_out, out, nullptr, M, EMBED, EMBED);
}

// Round 7
// 240.155 us; speedup vs baseline: 1.0110x; 1.0110x over previous
//
#include <hip/hip_runtime.h>
#include <math.h>

#define EMBED   1024
#define THREEC  3072
#define NH      16
#define HD      64
#define NFEAT   64      // R * M = 2 * 32
#define RN      2
#define MM_     32
#define B_      2
#define T_      4096
#define L_      64      // chunk length
#define NC_     64      // T_ / L_
#define BH_     32      // B_ * NH

typedef __attribute__((ext_vector_type(8))) short bf16x8;
typedef __attribute__((ext_vector_type(4))) float f32x4;

__device__ __forceinline__ float bf2f(short s) {
    unsigned u = ((unsigned)(unsigned short)s) << 16;
    return __builtin_bit_cast(float, u);
}
__device__ __forceinline__ short f2bf(float f) {
    unsigned u = __builtin_bit_cast(unsigned, f);
    u += 0x7fff + ((u >> 16) & 1);
    return (short)(u >> 16);
}
__device__ __forceinline__ void gload16(const short* g, short* l) {
    __builtin_amdgcn_global_load_lds(
        (const __attribute__((address_space(1))) void*)g,
        (__attribute__((address_space(3))) void*)l, 16, 0, 0);
}

// ---------------------------------------------------------------------------
// f32 -> bf16 cast, 8 elems/thread
// ---------------------------------------------------------------------------
__global__ __launch_bounds__(256) void cast_kernel(
    const float* __restrict__ in, short* __restrict__ out, int n8)
{
    int i = blockIdx.x * 256 + threadIdx.x;
    if (i >= n8) return;
    const float4* p = (const float4*)in + (size_t)i * 2;
    float4 a = p[0], b = p[1];
    bf16x8 o = { f2bf(a.x), f2bf(a.y), f2bf(a.z), f2bf(a.w),
                 f2bf(b.x), f2bf(b.y), f2bf(b.z), f2bf(b.w) };
    *((bf16x8*)out + i) = o;
}

// ---------------------------------------------------------------------------
// omega [R,H,D,M] fp32 -> omgT[h][f=r*32+m][d] bf16 hi/lo split
// ---------------------------------------------------------------------------
__global__ __launch_bounds__(256) void omega_prep(
    const float* __restrict__ omega, short* __restrict__ hi, short* __restrict__ lo)
{
    int i = blockIdx.x * 256 + threadIdx.x;   // over H*F*D = 65536
    if (i >= NH * NFEAT * HD) return;
    int d = i & 63;
    int f = (i >> 6) & 63;
    int h = i >> 12;
    int r = f >> 5, m = f & 31;
    float w = omega[(((size_t)(r * NH + h) * HD + d) * MM_) + m];
    short a = f2bf(w);
    hi[i] = a;
    lo[i] = f2bf(w - bf2f(a));
}

// ---------------------------------------------------------------------------
// 8-phase 256x256 bf16 MFMA GEMM, m201 template (in-phase consume).
// BK=64 as 2 K-halves; 2 LDS dbufs (128 KiB); 512 thr = 8 waves (2x4),
// per-wave output 128x64 (acc[8][4]); single frag set af[4]/bfv[4].
// Phase odd : {RD A0-3 + B0-3 | 1 stage | BAR | lgkm0 | 16 MFMA}        BAR
// Phase even: {RD A4-7        | 1 stage | BAR | lgkm0 | 16 MFMA | vm8} BAR
// vmcnt(8) once per even phase: every staged region verified landed
// before its reader; every overwrite 1 barrier after its last read.
// Swizzle: granule g ^= (row>>1)&3 on stage-source and ds_read (conflict-
// free within 8-lane groups; verified r6: SQ_LDS_BANK_CONFLICT = 0).
// Requires M%256==0, N%256==0, K%128==0, K>=256.
// ---------------------------------------------------------------------------
__global__ __launch_bounds__(512) void gemm_8ph(
    const short* __restrict__ Ag,     // [M][K] bf16
    const short* __restrict__ Wg,     // [N][K] bf16
    const float* __restrict__ bias,   // [N]
    short* __restrict__ Cb,           // [M][N] bf16
    int M, int N, int K)
{
    __shared__ short LDS[65536];      // A: [0..32767], B: [32768..65535]

    const int tid  = threadIdx.x;
    const int nbn  = N >> 8;
    const int nwg  = gridDim.x;
    const int cpx  = nwg >> 3;                    // grid % 8 == 0
    const int bid  = blockIdx.x;
    const int swz  = (bid & 7) * cpx + (bid >> 3);
    const int bm   = (swz / nbn) << 8;
    const int bn   = (swz % nbn) << 8;

    const int lane = tid & 63;
    const int wid  = tid >> 6;
    const int wm   = wid >> 2;        // 0..1 (row half)
    const int wn   = wid & 3;         // 0..3 (col quarter)
    const int lr   = lane & 15;
    const int G    = lane >> 4;       // k-granule 0..3

    const int r2   = tid >> 2;        // staging row 0..127
    const int gsw  = (tid & 3) ^ ((r2 >> 1) & 3); // pre-swizzled source granule
    const int KT   = K >> 6;          // BK=64 tiles
    const int KT2  = KT >> 1;

    f32x4  acc[8][4] = {};
    bf16x8 af[4], bfv[4];

#define ST_A(buf, kh, kt) { \
        short* ldst = &LDS[((buf) * 2 + (kh)) * 8192]; \
        gload16(&Ag[(size_t)(bm + r2) * K + (kt) * 64 + (kh) * 32 + gsw * 8], \
                ldst + tid * 8); \
        gload16(&Ag[(size_t)(bm + 128 + r2) * K + (kt) * 64 + (kh) * 32 + gsw * 8], \
                ldst + 4096 + tid * 8); }
#define ST_B(buf, kh, kt) { \
        short* ldst = &LDS[32768 + ((buf) * 2 + (kh)) * 8192]; \
        gload16(&Wg[(size_t)(bn + r2) * K + (kt) * 64 + (kh) * 32 + gsw * 8], \
                ldst + tid * 8); \
        gload16(&Wg[(size_t)(bn + 128 + r2) * K + (kt) * 64 + (kh) * 32 + gsw * 8], \
                ldst + 4096 + tid * 8); }
#define RD_A4(buf, kh, frlo) { \
        const short* lsrc = &LDS[((buf) * 2 + (kh)) * 8192]; \
        _Pragma("unroll") \
        for (int q = 0; q < 4; ++q) { \
            const int row = wm * 128 + ((frlo) + q) * 16 + lr; \
            af[q] = *(const bf16x8*)&lsrc[row * 32 + ((G ^ ((row >> 1) & 3)) << 3)]; } }
#define RD_B4(buf, kh) { \
        const short* lsrc = &LDS[32768 + ((buf) * 2 + (kh)) * 8192]; \
        _Pragma("unroll") \
        for (int q = 0; q < 4; ++q) { \
            const int row = wn * 64 + q * 16 + lr; \
            bfv[q] = *(const bf16x8*)&lsrc[row * 32 + ((G ^ ((row >> 1) & 3)) << 3)]; } }
#define MM4(frlo) \
        _Pragma("unroll") \
        for (int q = 0; q < 4; ++q) \
            _Pragma("unroll") \
            for (int fc = 0; fc < 4; ++fc) \
                acc[(frlo) + q][fc] = __builtin_amdgcn_mfma_f32_16x16x32_bf16( \
                    af[q], bfv[fc], acc[(frlo) + q][fc], 0, 0, 0);
#define BAR   __builtin_amdgcn_s_barrier()
#define LGKM0 { asm volatile("s_waitcnt lgkmcnt(0)" ::: "memory"); \
                __builtin_amdgcn_sched_barrier(0); }
#define VM8   asm volatile("s_waitcnt vmcnt(8)" ::: "memory")
#define VM0   asm volatile("s_waitcnt vmcnt(0)" ::: "memory")
#define PRIO1 __builtin_amdgcn_s_setprio(1)
#define PRIO0 __builtin_amdgcn_s_setprio(0)

    // Prologue: stage kt0 fully + kt1 kh0; gate kt0-kh0 landed.
    ST_A(0, 0, 0); ST_B(0, 0, 0); ST_A(0, 1, 0); ST_B(0, 1, 0);
    ST_A(1, 0, 1); ST_B(1, 0, 1);
    VM8;
    BAR;

    #pragma unroll 1
    for (int i = 0; i < KT2; ++i) {
        const int k1 = 2 * i + 1, k2 = 2 * i + 2, k3 = 2 * i + 3;
        const bool st2 = k2 < KT, st3 = k3 < KT;
        // ph1: buf0 kh0 fr0-3
        RD_A4(0, 0, 0); RD_B4(0, 0);
        ST_A(1, 1, k1);
        BAR; LGKM0; PRIO1; MM4(0); PRIO0; BAR;
        // ph2: buf0 kh0 fr4-7
        RD_A4(0, 0, 4);
        ST_B(1, 1, k1);
        BAR; LGKM0; PRIO1; MM4(4); PRIO0; VM8; BAR;
        // ph3: buf0 kh1 fr0-3
        RD_A4(0, 1, 0); RD_B4(0, 1);
        if (st2) ST_A(0, 0, k2);
        BAR; LGKM0; PRIO1; MM4(0); PRIO0; BAR;
        // ph4: buf0 kh1 fr4-7
        RD_A4(0, 1, 4);
        if (st2) ST_B(0, 0, k2);
        BAR; LGKM0; PRIO1; MM4(4); PRIO0; VM8; BAR;
        // ph5: buf1 kh0 fr0-3
        RD_A4(1, 0, 0); RD_B4(1, 0);
        if (st2) ST_A(0, 1, k2);
        BAR; LGKM0; PRIO1; MM4(0); PRIO0; BAR;
        // ph6: buf1 kh0 fr4-7
        RD_A4(1, 0, 4);
        if (st2) ST_B(0, 1, k2);
        BAR; LGKM0; PRIO1; MM4(4); PRIO0;
        if (st2) { VM8; } else { VM0; }
        BAR;
        // ph7: buf1 kh1 fr0-3
        RD_A4(1, 1, 0); RD_B4(1, 1);
        if (st3) ST_A(1, 0, k3);
        BAR; LGKM0; PRIO1; MM4(0); PRIO0; BAR;
        // ph8: buf1 kh1 fr4-7
        RD_A4(1, 1, 4);
        if (st3) ST_B(1, 0, k3);
        BAR; LGKM0; PRIO1; MM4(4); PRIO0; VM8; BAR;
    }
    VM0;          // drain all staging DMA before LDS reuse
    BAR;

#undef ST_A
#undef ST_B
#undef RD_A4
#undef RD_B4
#undef MM4

    // Epilogue: 2-pass LDS transpose -> coalesced bf16x8 row stores.
    float bv[4];
    #pragma unroll
    for (int fc = 0; fc < 4; ++fc)
        bv[fc] = bias[bn + wn * 64 + fc * 16 + lr];

    short* E = (short*)LDS;           // [128][264]
    #pragma unroll 1
    for (int pass = 0; pass < 2; ++pass) {
        __syncthreads();
        if (wm == pass) {
            #pragma unroll
            for (int fr = 0; fr < 8; ++fr)
                #pragma unroll
                for (int fc = 0; fc < 4; ++fc) {
                    const int col = wn * 64 + fc * 16 + lr;
                    #pragma unroll
                    for (int j = 0; j < 4; ++j) {
                        const int rl = fr * 16 + G * 4 + j;
                        E[rl * 264 + col] = f2bf(acc[fr][fc][j] + bv[fc]);
                    }
                }
        }
        __syncthreads();
        #pragma unroll
        for (int i = 0; i < 8; ++i) {
            const int idx = i * 512 + tid;        // 0..4095
            const int rl  = idx >> 5;
            const int c8  = idx & 31;
            bf16x8 v = *(const bf16x8*)&E[rl * 264 + c8 * 8];
            *(bf16x8*)&Cb[(size_t)(bm + pass * 128 + rl) * N + bn + c8 * 8] = v;
        }
    }
}

// ---------------------------------------------------------------------------
// bf16 MFMA GEMM (m97 structure) — used for the output projection
// ---------------------------------------------------------------------------
template<int OUTBF>
__global__ __launch_bounds__(256) void gemm_bf16(
    const short* __restrict__ A,      // [M][K] bf16
    const short* __restrict__ W,      // [N][K] bf16
    const float* __restrict__ bias,   // [N]
    float* __restrict__ Cf, short* __restrict__ Cb,
    int M, int N, int K)
{
    __shared__ short lA[2][128 * 32];
    __shared__ short lB[2][128 * 32];
    const int tid  = threadIdx.x;
    const int bm   = blockIdx.y * 128;
    const int bn   = blockIdx.x * 128;
    const int lane = tid & 63;
    const int wave = tid >> 6;
    const int row0 = (wave >> 1) * 64;
    const int col0 = (wave & 1) * 64;
    const int lr   = lane & 15;
    const int kg8  = (lane >> 4) * 8;

    f32x4 acc[4][4] = {};

#define STAGE(buf, k0)                                                        \
    {                                                                         \
        _Pragma("unroll")                                                     \
        for (int i = 0; i < 2; ++i) {                                         \
            int idx = i * 256 + tid;                                          \
            int row = idx >> 2, kq = (idx & 3) * 8;                           \
            gload16(&A[(size_t)(bm + row) * K + (k0) + kq], &lA[buf][idx * 8]); \
            gload16(&W[(size_t)(bn + row) * K + (k0) + kq], &lB[buf][idx * 8]); \
        }                                                                     \
    }

    const int KT = K >> 5;
    STAGE(0, 0);
    __syncthreads();
    int cur = 0;
    for (int kt = 0; kt < KT; ++kt) {
        if (kt + 1 < KT) STAGE(cur ^ 1, (kt + 1) * 32);
        const short* As = lA[cur];
        const short* Bs = lB[cur];
        bf16x8 af[4], bfr[4];
        #pragma unroll
        for (int m = 0; m < 4; ++m)
            af[m] = *(const bf16x8*)&As[(row0 + m * 16 + lr) * 32 + kg8];
        #pragma unroll
        for (int n = 0; n < 4; ++n)
            bfr[n] = *(const bf16x8*)&Bs[(col0 + n * 16 + lr) * 32 + kg8];
        #pragma unroll
        for (int m = 0; m < 4; ++m)
            #pragma unroll
            for (int n = 0; n < 4; ++n)
                acc[m][n] = __builtin_amdgcn_mfma_f32_16x16x32_bf16(
                    af[m], bfr[n], acc[m][n], 0, 0, 0);
        __syncthreads();
        cur ^= 1;
    }
#undef STAGE

    #pragma unroll
    for (int n = 0; n < 4; ++n) {
        const int col = bn + col0 + n * 16 + (lane & 15);
        const float bvv = bias[col];
        #pragma unroll
        for (int m = 0; m < 4; ++m) {
            const int rbase = bm + row0 + m * 16 + (lane >> 4) * 4;
            #pragma unroll
            for (int j = 0; j < 4; ++j) {
                const float v = acc[m][n][j] + bvv;
                if (OUTBF) Cb[(size_t)(rbase + j) * N + col] = f2bf(v);
                else       Cf[(size_t)(rbase + j) * N + col] = v;
            }
        }
    }
}

// ---------------------------------------------------------------------------
// Feature map (MFMA), writing bf16 qf/kf.
// ---------------------------------------------------------------------------
__global__ __launch_bounds__(256) void features_mfma(
    const short* __restrict__ qkvb,       // [B, T, 3C] bf16
    const short* __restrict__ omgH,       // [H][64f][64d] bf16 (hi)
    const short* __restrict__ omgL,       // [H][64f][64d] bf16 (lo)
    const float* __restrict__ qn,
    const float* __restrict__ qw,
    short* __restrict__ qf,               // [BH, T, 64] bf16
    short* __restrict__ kf)
{
    __shared__ short zq[64][72];
    __shared__ short zk[64][72];
    __shared__ short omh[64][72];
    __shared__ short oml[64][72];
    __shared__ float invn[2][64];

    const int tid = threadIdx.x;
    const int bh  = blockIdx.x >> 6;      // 0..31
    const int tb  = blockIdx.x & 63;      // 0..63
    const int b   = bh >> 4, h = bh & 15;
    const int t0  = tb * 64;

    {
        const int row = tid >> 2;
        const int c0  = (tid & 3) * 16;
        const size_t zbase = ((size_t)(b * T_ + t0 + row)) * THREEC + h * HD + c0;
        const size_t obase = ((size_t)h * NFEAT + row) * HD + c0;
        *(bf16x8*)&zq[row][c0]      = *(const bf16x8*)&qkvb[zbase];
        *(bf16x8*)&zq[row][c0 + 8]  = *(const bf16x8*)&qkvb[zbase + 8];
        *(bf16x8*)&zk[row][c0]      = *(const bf16x8*)&qkvb[zbase + EMBED];
        *(bf16x8*)&zk[row][c0 + 8]  = *(const bf16x8*)&qkvb[zbase + EMBED + 8];
        *(bf16x8*)&omh[row][c0]     = *(const bf16x8*)&omgH[obase];
        *(bf16x8*)&omh[row][c0 + 8] = *(const bf16x8*)&omgH[obase + 8];
        *(bf16x8*)&oml[row][c0]     = *(const bf16x8*)&omgL[obase];
        *(bf16x8*)&oml[row][c0 + 8] = *(const bf16x8*)&omgL[obase + 8];
    }
    __syncthreads();

    {
        const int t = tid >> 2;
        const int q = tid & 3;
        #pragma unroll
        for (int p = 0; p < 2; ++p) {
            const short* Z = p ? &zk[t][q * 16] : &zq[t][q * 16];
            float ss = 0.0f;
            #pragma unroll
            for (int j = 0; j < 16; ++j) { float v = bf2f(Z[j]); ss += v * v; }
            ss += __shfl_xor(ss, 1, 64);
            ss += __shfl_xor(ss, 2, 64);
            if (q == 0) invn[p][t] = 1.0f / fmaxf(sqrtf(ss), 1e-12f);
        }
    }
    __syncthreads();

    const int wave = tid >> 6;
    const int lane = tid & 63;
    const int p    = wave >> 1;           // 0 = q, 1 = k
    const int half = wave & 1;            // token half
    const short (*Z)[72] = p ? zk : zq;

    const float s0 = qn[0], s1 = qn[1];
    const float sq2s0 = sqrtf(2.0f * fmaxf(s0, 0.0f));
    const float sq2s1 = sqrtf(2.0f * fmaxf(s1, 0.0f));
    const float sc0 = sqrtf(fmaxf(qw[0], 0.0f)) * (1.0f / 32.0f);
    const float sc1 = sqrtf(fmaxf(qw[1], 0.0f)) * (1.0f / 32.0f);

    const int lr  = lane & 15;
    const int kg8 = (lane >> 4) * 8;

    f32x4 acc[2][4] = {};
    #pragma unroll
    for (int kk = 0; kk < 2; ++kk) {
        bf16x8 a[2], bh8[4], bl8[4];
        #pragma unroll
        for (int m = 0; m < 2; ++m)
            a[m] = *(const bf16x8*)&Z[half * 32 + m * 16 + lr][kk * 32 + kg8];
        #pragma unroll
        for (int n = 0; n < 4; ++n) {
            bh8[n] = *(const bf16x8*)&omh[n * 16 + lr][kk * 32 + kg8];
            bl8[n] = *(const bf16x8*)&oml[n * 16 + lr][kk * 32 + kg8];
        }
        #pragma unroll
        for (int m = 0; m < 2; ++m)
            #pragma unroll
            for (int n = 0; n < 4; ++n) {
                acc[m][n] = __builtin_amdgcn_mfma_f32_16x16x32_bf16(
                    a[m], bh8[n], acc[m][n], 0, 0, 0);
                acc[m][n] = __builtin_amdgcn_mfma_f32_16x16x32_bf16(
                    a[m], bl8[n], acc[m][n], 0, 0, 0);
            }
    }

    short* dstbase = (p ? kf : qf) + ((size_t)bh * T_ + t0) * NFEAT;
    #pragma unroll
    for (int n = 0; n < 4; ++n) {
        const int f = n * 16 + (lane & 15);
        const float s_r   = (n < 2) ? s0 : s1;
        const float sq2s  = (n < 2) ? sq2s0 : sq2s1;
        const float scale = (n < 2) ? sc0 : sc1;
        #pragma unroll
        for (int m = 0; m < 2; ++m) {
            const int tb4 = half * 32 + m * 16 + (lane >> 4) * 4;
            #pragma unroll
            for (int j = 0; j < 4; ++j) {
                const int t = tb4 + j;
                const float proj = acc[m][n][j] * invn[p][t];
                const float arg = fminf(fmaxf(proj * sq2s - s_r, -20.0f), 20.0f);
                const float val = proj * proj * __expf(arg) * scale;
                dstbase[(size_t)t * NFEAT + f] = f2bf(val);
            }
        }
    }
}

// ---------------------------------------------------------------------------
// Per-chunk KV sums. Writes cKV TRANSPOSED: [chunk][d][f] = S[f][d].
// ---------------------------------------------------------------------------
__global__ __launch_bounds__(256) void chunk_sums(
    const short* __restrict__ kf,         // bf16
    const short* __restrict__ qkvb,
    float* __restrict__ cKV,              // [BH*NC, 64d, 64f]
    float* __restrict__ cK)               // [BH*NC, 64]
{
    __shared__ float kfs[64][64];
    __shared__ float vs[64][64];
    float (*st)[65] = (float(*)[65])kfs;  // reuse after compute

    const int tid = threadIdx.x;
    const int chunk = blockIdx.x;
    const int bh = chunk >> 6, c = chunk & 63;
    const int b = bh >> 4, h = bh & 15;
    const int t0 = c * L_;

    {
        const int row = tid >> 2;
        const int c0  = (tid & 3) * 16;
        const short* krow = kf + ((size_t)bh * T_ + t0 + row) * NFEAT;
        const short* vrow = qkvb + ((size_t)(b * T_ + t0 + row)) * THREEC + 2 * EMBED + h * HD;
        bf16x8 k0 = *(const bf16x8*)&krow[c0], k1 = *(const bf16x8*)&krow[c0 + 8];
        bf16x8 v0 = *(const bf16x8*)&vrow[c0], v1 = *(const bf16x8*)&vrow[c0 + 8];
        #pragma unroll
        for (int j = 0; j < 8; ++j) {
            kfs[row][c0 + j]     = bf2f(k0[j]);
            kfs[row][c0 + 8 + j] = bf2f(k1[j]);
            vs[row][c0 + j]      = bf2f(v0[j]);
            vs[row][c0 + 8 + j]  = bf2f(v1[j]);
        }
    }
    __syncthreads();

    const int f  = tid >> 2;
    const int d0 = (tid & 3) * 16;
    float acc[16] = {};
    float ks = 0.0f;
    for (int t = 0; t < L_; ++t) {
        const float kft = kfs[t][f];
        ks += kft;
        #pragma unroll
        for (int j = 0; j < 16; ++j) acc[j] += kft * vs[t][d0 + j];
    }
    if ((tid & 3) == 0) cK[(size_t)chunk * NFEAT + f] = ks;
    __syncthreads();   // done reading kfs/vs

    #pragma unroll
    for (int j = 0; j < 16; ++j) st[f][d0 + j] = acc[j];
    __syncthreads();

    {
        const int d  = tid >> 2;
        const int f0 = (tid & 3) * 16;
        float* dst = cKV + (size_t)chunk * (NFEAT * HD) + tid * 16;
        #pragma unroll
        for (int q = 0; q < 4; ++q) {
            float4 o;
            o.x = st[f0 + q * 4 + 0][d];
            o.y = st[f0 + q * 4 + 1][d];
            o.z = st[f0 + q * 4 + 2][d];
            o.w = st[f0 + q * 4 + 3][d];
            *(float4*)&dst[q * 4] = o;
        }
    }
}

// ---------------------------------------------------------------------------
// Exclusive prefix over chunks. grid: BH_*4 blocks; depth-2 prefetch.
// ---------------------------------------------------------------------------
__global__ __launch_bounds__(256) void prefix_scan(
    float* __restrict__ cKV, float* __restrict__ cK)
{
    const int bh  = blockIdx.x >> 2;
    const int sl  = blockIdx.x & 3;
    const int tid = threadIdx.x;
    float4* base = (float4*)(cKV + (size_t)bh * NC_ * (NFEAT * HD) + sl * 1024) + tid;
    float4 n0 = base[0];
    float4 n1 = base[1024];
    float4 pref; pref.x = pref.y = pref.z = pref.w = 0.0f;
    for (int c = 0; c < NC_; ++c) {
        float4 cur = n0;
        n0 = n1;
        if (c + 2 < NC_) n1 = base[(size_t)(c + 2) * 1024];
        else { n1.x = n1.y = n1.z = n1.w = 0.0f; }
        base[(size_t)c * 1024] = pref;
        pref.x += cur.x; pref.y += cur.y; pref.z += cur.z; pref.w += cur.w;
    }
    if (sl == 0 && tid < 64) {
        float* kb = cK + (size_t)bh * NC_ * NFEAT + tid;
        float m0 = kb[0];
        float m1 = kb[64];
        float p = 0.0f;
        for (int c = 0; c < NC_; ++c) {
            float cu = m0;
            m0 = m1;
            m1 = (c + 2 < NC_) ? kb[(size_t)(c + 2) * 64] : 0.0f;
            kb[(size_t)c * 64] = p;
            p += cu;
        }
    }
}

// ---------------------------------------------------------------------------
// Intra-chunk causal attention via MFMA. 4 waves, each owns a 16-row band.
// ---------------------------------------------------------------------------
__global__ __launch_bounds__(256) void intra_mfma(
    const short* __restrict__ qf,         // [BH,T,64] bf16
    const short* __restrict__ kf,
    const short* __restrict__ qkvb,       // v region (bf16)
    const float* __restrict__ cKV,        // [chunk][d][f] prefix fp32
    const float* __restrict__ cK,         // [chunk][f] prefix fp32
    short* __restrict__ attnb)            // [B*T, EMBED] bf16
{
    __shared__ short Qs[64][72];
    __shared__ short Ks[64][72];
    __shared__ short Vt[64][72];          // V^T: [d][t]
    __shared__ short Pp[64][72];          // KVp^T: [d][f]
    __shared__ short At[64][72];          // masked A: [t][s]
    __shared__ float rs_l[64], qkp_l[64], cKp[64];

    const int tid = threadIdx.x;
    const int chunk = blockIdx.x;
    const int bh = chunk >> 6, c = chunk & 63;
    const int b = bh >> 4, h = bh & 15;
    const int t0 = c * L_;

    {
        const int row = tid >> 2;
        const int c0  = (tid & 3) * 16;
        const short* qrow = qf + ((size_t)bh * T_ + t0 + row) * NFEAT;
        const short* krow = kf + ((size_t)bh * T_ + t0 + row) * NFEAT;
        const short* vrow = qkvb + ((size_t)(b * T_ + t0 + row)) * THREEC + 2 * EMBED + h * HD;
        *(bf16x8*)&Qs[row][c0]     = *(const bf16x8*)&qrow[c0];
        *(bf16x8*)&Qs[row][c0 + 8] = *(const bf16x8*)&qrow[c0 + 8];
        *(bf16x8*)&Ks[row][c0]     = *(const bf16x8*)&krow[c0];
        *(bf16x8*)&Ks[row][c0 + 8] = *(const bf16x8*)&krow[c0 + 8];
        bf16x8 v0 = *(const bf16x8*)&vrow[c0], v1 = *(const bf16x8*)&vrow[c0 + 8];
        #pragma unroll
        for (int j = 0; j < 8; ++j) {
            Vt[c0 + j][row]     = v0[j];
            Vt[c0 + 8 + j][row] = v1[j];
        }
        const float* pbase = cKV + (size_t)chunk * (NFEAT * HD) + tid * 16;
        float4 p0 = *(const float4*)&pbase[0],  p1 = *(const float4*)&pbase[4];
        float4 p2 = *(const float4*)&pbase[8],  p3 = *(const float4*)&pbase[12];
        bf16x8 o0 = { f2bf(p0.x), f2bf(p0.y), f2bf(p0.z), f2bf(p0.w),
                      f2bf(p1.x), f2bf(p1.y), f2bf(p1.z), f2bf(p1.w) };
        bf16x8 o1 = { f2bf(p2.x), f2bf(p2.y), f2bf(p2.z), f2bf(p2.w),
                      f2bf(p3.x), f2bf(p3.y), f2bf(p3.z), f2bf(p3.w) };
        *(bf16x8*)&Pp[row][c0]     = o0;
        *(bf16x8*)&Pp[row][c0 + 8] = o1;
        if (tid < 64) cKp[tid] = cK[(size_t)chunk * NFEAT + tid];
    }
    __syncthreads();

    const int wave = tid >> 6;
    const int lane = tid & 63;
    const int lr   = lane & 15;
    const int kg   = (lane >> 4) * 8;
    const int r0   = wave * 16;

    bf16x8 aq[2];
    aq[0] = *(const bf16x8*)&Qs[r0 + lr][kg];
    aq[1] = *(const bf16x8*)&Qs[r0 + lr][32 + kg];
    f32x4 accA[4] = {};
    #pragma unroll
    for (int n = 0; n < 4; ++n) {
        accA[n] = __builtin_amdgcn_mfma_f32_16x16x32_bf16(
            aq[0], *(const bf16x8*)&Ks[n * 16 + lr][kg], accA[n], 0, 0, 0);
        accA[n] = __builtin_amdgcn_mfma_f32_16x16x32_bf16(
            aq[1], *(const bf16x8*)&Ks[n * 16 + lr][32 + kg], accA[n], 0, 0, 0);
    }
    float rsum[4] = {0.0f, 0.0f, 0.0f, 0.0f};
    #pragma unroll
    for (int n = 0; n < 4; ++n) {
        const int s = n * 16 + lr;
        #pragma unroll
        for (int j = 0; j < 4; ++j) {
            const int t = r0 + (lane >> 4) * 4 + j;
            const float a = (s <= t) ? accA[n][j] : 0.0f;
            rsum[j] += a;
            At[t][s] = f2bf(a);
        }
    }
    #pragma unroll
    for (int j = 0; j < 4; ++j) {
        rsum[j] += __shfl_xor(rsum[j], 1, 64);
        rsum[j] += __shfl_xor(rsum[j], 2, 64);
        rsum[j] += __shfl_xor(rsum[j], 4, 64);
        rsum[j] += __shfl_xor(rsum[j], 8, 64);
    }
    if (lr == 0) {
        #pragma unroll
        for (int j = 0; j < 4; ++j) rs_l[r0 + (lane >> 4) * 4 + j] = rsum[j];
    }

    {
        const int t  = tid >> 2;
        const int fq = (tid & 3) * 16;
        float s = 0.0f;
        #pragma unroll
        for (int j = 0; j < 16; ++j) s += bf2f(Qs[t][fq + j]) * cKp[fq + j];
        s += __shfl_xor(s, 1, 64);
        s += __shfl_xor(s, 2, 64);
        if ((tid & 3) == 0) qkp_l[t] = s;
    }
    __syncthreads();

    bf16x8 aa[2];
    aa[0] = *(const bf16x8*)&At[r0 + lr][kg];
    aa[1] = *(const bf16x8*)&At[r0 + lr][32 + kg];
    f32x4 acc[4] = {};
    #pragma unroll
    for (int n = 0; n < 4; ++n) {
        acc[n] = __builtin_amdgcn_mfma_f32_16x16x32_bf16(
            aa[0], *(const bf16x8*)&Vt[n * 16 + lr][kg], acc[n], 0, 0, 0);
        acc[n] = __builtin_amdgcn_mfma_f32_16x16x32_bf16(
            aa[1], *(const bf16x8*)&Vt[n * 16 + lr][32 + kg], acc[n], 0, 0, 0);
        acc[n] = __builtin_amdgcn_mfma_f32_16x16x32_bf16(
            aq[0], *(const bf16x8*)&Pp[n * 16 + lr][kg], acc[n], 0, 0, 0);
        acc[n] = __builtin_amdgcn_mfma_f32_16x16x32_bf16(
            aq[1], *(const bf16x8*)&Pp[n * 16 + lr][32 + kg], acc[n], 0, 0, 0);
    }

    float inv[4];
    #pragma unroll
    for (int j = 0; j < 4; ++j) {
        const int t = r0 + (lane >> 4) * 4 + j;
        inv[j] = 1.0f / fmaxf(rs_l[t] + qkp_l[t], 1e-6f);
    }
    #pragma unroll
    for (int n = 0; n < 4; ++n) {
        const int d = n * 16 + lr;
        #pragma unroll
        for (int j = 0; j < 4; ++j) {
            const int t = r0 + (lane >> 4) * 4 + j;
            attnb[((size_t)(b * T_ + t0 + t)) * EMBED + h * HD + d] =
                f2bf(acc[n][j] * inv[j]);
        }
    }
}

// ---------------------------------------------------------------------------
extern "C" void kernel_launch(void* const* d_in, const int* in_sizes, int n_in,
                              void* d_out, int out_size, void* d_ws, size_t ws_size,
                              hipStream_t stream)
{
    const float* x     = (const float*)d_in[0];
    const float* w_qkv = (const float*)d_in[1];
    const float* b_qkv = (const float*)d_in[2];
    const float* w_out = (const float*)d_in[3];
    const float* b_out = (const float*)d_in[4];
    const float* omega = (const float*)d_in[5];
    const float* qn    = (const float*)d_in[6];
    const float* qw    = (const float*)d_in[7];
    float* out = (float*)d_out;

    // workspace layout (shorts first, then floats)
    short* xb    = (short*)d_ws;               //  8,388,608
    short* wqb   = xb    + 8388608;            //  3,145,728
    short* wob   = wqb   + 3145728;            //  1,048,576
    short* qkvb  = wob   + 1048576;            // 25,165,824
    short* attnb = qkvb  + 25165824;           //  8,388,608
    short* omgH  = attnb + 8388608;            //     65,536
    short* omgL  = omgH  + 65536;              //     65,536
    short* qfb   = omgL  + 65536;              //  8,388,608
    short* kfb   = qfb   + 8388608;            //  8,388,608
    float* cKV   = (float*)(kfb + 8388608);    //  8,388,608 floats
    float* cK    = cKV + 8388608;              //    131,072 floats

    const int M = B_ * T_;   // 8192

    cast_kernel<<<dim3(8388608 / 8 / 256), 256, 0, stream>>>(x, xb, 8388608 / 8);
    cast_kernel<<<dim3(3145728 / 8 / 256), 256, 0, stream>>>(w_qkv, wqb, 3145728 / 8);
    cast_kernel<<<dim3(1048576 / 8 / 256), 256, 0, stream>>>(w_out, wob, 1048576 / 8);
    omega_prep<<<dim3(256), 256, 0, stream>>>(omega, omgH, omgL);

    // 1. qkv = x @ w_qkv^T + b_qkv  (bf16 out) — 8-phase 256^2 kernel
    gemm_8ph<<<dim3((M / 256) * (THREEC / 256)), 512, 0, stream>>>(
        xb, wqb, b_qkv, qkvb, M, THREEC, EMBED);
    // 2. features (MFMA, bf16 out)
    features_mfma<<<dim3(BH_ * (T_ / 64)), 256, 0, stream>>>(
        qkvb, omgH, omgL, qn, qw, qfb, kfb);
    // 3. per-chunk KV sums (transposed cKV)
    chunk_sums<<<dim3(BH_ * NC_), 256, 0, stream>>>(kfb, qkvb, cKV, cK);
    // 4. exclusive prefix over chunks
    prefix_scan<<<dim3(BH_ * 4), 256, 0, stream>>>(cKV, cK);
    // 5. intra-chunk attention (MFMA) -> bf16 attn [B*T, C]
    intra_mfma<<<dim3(BH_ * NC_), 256, 0, stream>>>(qfb, kfb, qkvb, cKV, cK, attnb);
    // 6. out = attn @ w_out^T + b_out (fp32 out)
    gemm_bf16<0><<<dim3(EMBED / 128, M / 128), 256, 0, stream>>>(
        attnb, wob, b_out, out, nullptr, M, EMBED, EMBED);
}

// Round 8
// 170.713 us; speedup vs baseline: 1.4223x; 1.4068x over previous
//
#include <hip/hip_runtime.h>
#include <math.h>

#define EMBED   1024
#define THREEC  3072
#define NH      16
#define HD      64
#define NFEAT   64      // R * M = 2 * 32
#define RN      2
#define MM_     32
#define B_      2
#define T_      4096
#define L_      64      // chunk length
#define NC_     64      // T_ / L_
#define BH_     32      // B_ * NH

typedef __attribute__((ext_vector_type(8))) short bf16x8;
typedef __attribute__((ext_vector_type(4))) float f32x4;

__device__ __forceinline__ float bf2f(short s) {
    unsigned u = ((unsigned)(unsigned short)s) << 16;
    return __builtin_bit_cast(float, u);
}
__device__ __forceinline__ short f2bf(float f) {
    unsigned u = __builtin_bit_cast(unsigned, f);
    u += 0x7fff + ((u >> 16) & 1);
    return (short)(u >> 16);
}
__device__ __forceinline__ void gload16(const short* g, short* l) {
    __builtin_amdgcn_global_load_lds(
        (const __attribute__((address_space(1))) void*)g,
        (__attribute__((address_space(3))) void*)l, 16, 0, 0);
}

// ---------------------------------------------------------------------------
// Fused prep: f32->bf16 casts for x, w_qkv, w_out (8 elems/thread) + omega
// hi/lo transpose prep (1 elem/thread appended range).
// ---------------------------------------------------------------------------
#define NV_X   1048576            // 8388608 / 8
#define NV_WQ  393216             // 3145728 / 8
#define NV_WO  131072             // 1048576 / 8
#define NV_ALL (NV_X + NV_WQ + NV_WO)
__global__ __launch_bounds__(256) void prep_kernel(
    const float* __restrict__ x, const float* __restrict__ wq,
    const float* __restrict__ wo, const float* __restrict__ omega,
    short* __restrict__ xb, short* __restrict__ wqb, short* __restrict__ wob,
    short* __restrict__ omgH, short* __restrict__ omgL)
{
    int i = blockIdx.x * 256 + threadIdx.x;
    if (i < NV_ALL) {
        const float* src; short* dst; int k;
        if (i < NV_X)            { src = x;  dst = xb;  k = i; }
        else if (i < NV_X+NV_WQ) { src = wq; dst = wqb; k = i - NV_X; }
        else                     { src = wo; dst = wob; k = i - NV_X - NV_WQ; }
        const float4* p = (const float4*)src + (size_t)k * 2;
        float4 a = p[0], b = p[1];
        bf16x8 o = { f2bf(a.x), f2bf(a.y), f2bf(a.z), f2bf(a.w),
                     f2bf(b.x), f2bf(b.y), f2bf(b.z), f2bf(b.w) };
        *((bf16x8*)dst + k) = o;
    } else {
        int j = i - NV_ALL;               // 0..65535 over H*F*D
        if (j < NH * NFEAT * HD) {
            int d = j & 63;
            int f = (j >> 6) & 63;
            int h = j >> 12;
            int r = f >> 5, m = f & 31;
            float w = omega[(((size_t)(r * NH + h) * HD + d) * MM_) + m];
            short a = f2bf(w);
            omgH[j] = a;
            omgL[j] = f2bf(w - bf2f(a));
        }
    }
}

// ---------------------------------------------------------------------------
// bf16 MFMA GEMM (m97 structure): 128x128 tile, BK=32, 256 thr (4 waves,
// each 64x64), global_load_lds w16, double-buffered LDS.
// C[m,n] = sum_k A[m*K+k] * W[n*K+k] + bias[n]. OUTBF: bf16 vs fp32 C.
// ---------------------------------------------------------------------------
template<int OUTBF>
__global__ __launch_bounds__(256) void gemm_bf16(
    const short* __restrict__ A,      // [M][K] bf16
    const short* __restrict__ W,      // [N][K] bf16
    const float* __restrict__ bias,   // [N]
    float* __restrict__ Cf, short* __restrict__ Cb,
    int M, int N, int K)
{
    __shared__ short lA[2][128 * 32];
    __shared__ short lB[2][128 * 32];
    const int tid  = threadIdx.x;
    const int bm   = blockIdx.y * 128;
    const int bn   = blockIdx.x * 128;
    const int lane = tid & 63;
    const int wave = tid >> 6;
    const int row0 = (wave >> 1) * 64;
    const int col0 = (wave & 1) * 64;
    const int lr   = lane & 15;
    const int kg8  = (lane >> 4) * 8;

    f32x4 acc[4][4] = {};

#define STAGE(buf, k0)                                                        \
    {                                                                         \
        _Pragma("unroll")                                                     \
        for (int i = 0; i < 2; ++i) {                                         \
            int idx = i * 256 + tid;                                          \
            int row = idx >> 2, kq = (idx & 3) * 8;                           \
            gload16(&A[(size_t)(bm + row) * K + (k0) + kq], &lA[buf][idx * 8]); \
            gload16(&W[(size_t)(bn + row) * K + (k0) + kq], &lB[buf][idx * 8]); \
        }                                                                     \
    }

    const int KT = K >> 5;
    STAGE(0, 0);
    __syncthreads();
    int cur = 0;
    for (int kt = 0; kt < KT; ++kt) {
        if (kt + 1 < KT) STAGE(cur ^ 1, (kt + 1) * 32);
        const short* As = lA[cur];
        const short* Bs = lB[cur];
        bf16x8 af[4], bfr[4];
        #pragma unroll
        for (int m = 0; m < 4; ++m)
            af[m] = *(const bf16x8*)&As[(row0 + m * 16 + lr) * 32 + kg8];
        #pragma unroll
        for (int n = 0; n < 4; ++n)
            bfr[n] = *(const bf16x8*)&Bs[(col0 + n * 16 + lr) * 32 + kg8];
        #pragma unroll
        for (int m = 0; m < 4; ++m)
            #pragma unroll
            for (int n = 0; n < 4; ++n)
                acc[m][n] = __builtin_amdgcn_mfma_f32_16x16x32_bf16(
                    af[m], bfr[n], acc[m][n], 0, 0, 0);
        __syncthreads();
        cur ^= 1;
    }
#undef STAGE

    #pragma unroll
    for (int n = 0; n < 4; ++n) {
        const int col = bn + col0 + n * 16 + (lane & 15);
        const float bvv = bias[col];
        #pragma unroll
        for (int m = 0; m < 4; ++m) {
            const int rbase = bm + row0 + m * 16 + (lane >> 4) * 4;
            #pragma unroll
            for (int j = 0; j < 4; ++j) {
                const float v = acc[m][n][j] + bvv;
                if (OUTBF) Cb[(size_t)(rbase + j) * N + col] = f2bf(v);
                else       Cf[(size_t)(rbase + j) * N + col] = v;
            }
        }
    }
}

// ---------------------------------------------------------------------------
// Fused feature map + per-chunk KV sums. One block = one (bh, chunk).
// Phase 1: proj = z @ omgT (hi+lo MFMA), feature transform -> qf/kf global.
// Phase 2: k-waves write kfT into zq region, all threads write vT into zk
//          region; 8 MFMAs/wave compute S[f][d] -> cKV[chunk][d][f]; cK sums.
// ---------------------------------------------------------------------------
__global__ __launch_bounds__(256) void features_chunk(
    const short* __restrict__ qkvb,       // [B, T, 3C] bf16
    const short* __restrict__ omgH,       // [H][64f][64d] bf16 (hi)
    const short* __restrict__ omgL,       // [H][64f][64d] bf16 (lo)
    const float* __restrict__ qn,
    const float* __restrict__ qw,
    short* __restrict__ qf,               // [BH, T, 64] bf16
    short* __restrict__ kf,
    float* __restrict__ cKV,              // [BH*NC, 64d, 64f] (per-chunk S^T)
    float* __restrict__ cK)               // [BH*NC, 64]
{
    __shared__ short zq[64][72];
    __shared__ short zk[64][72];
    __shared__ short omh[64][72];
    __shared__ short oml[64][72];
    __shared__ float invn[2][64];

    const int tid   = threadIdx.x;
    const int chunk = blockIdx.x;         // bh*64 + c
    const int bh    = chunk >> 6;         // 0..31
    const int c     = chunk & 63;         // 0..63
    const int b     = bh >> 4, h = bh & 15;
    const int t0    = c * 64;

    {
        const int row = tid >> 2;
        const int c0  = (tid & 3) * 16;
        const size_t zbase = ((size_t)(b * T_ + t0 + row)) * THREEC + h * HD + c0;
        const size_t obase = ((size_t)h * NFEAT + row) * HD + c0;
        *(bf16x8*)&zq[row][c0]      = *(const bf16x8*)&qkvb[zbase];
        *(bf16x8*)&zq[row][c0 + 8]  = *(const bf16x8*)&qkvb[zbase + 8];
        *(bf16x8*)&zk[row][c0]      = *(const bf16x8*)&qkvb[zbase + EMBED];
        *(bf16x8*)&zk[row][c0 + 8]  = *(const bf16x8*)&qkvb[zbase + EMBED + 8];
        *(bf16x8*)&omh[row][c0]     = *(const bf16x8*)&omgH[obase];
        *(bf16x8*)&omh[row][c0 + 8] = *(const bf16x8*)&omgH[obase + 8];
        *(bf16x8*)&oml[row][c0]     = *(const bf16x8*)&omgL[obase];
        *(bf16x8*)&oml[row][c0 + 8] = *(const bf16x8*)&omgL[obase + 8];
    }
    __syncthreads();

    {
        const int t = tid >> 2;
        const int q = tid & 3;
        #pragma unroll
        for (int p = 0; p < 2; ++p) {
            const short* Z = p ? &zk[t][q * 16] : &zq[t][q * 16];
            float ss = 0.0f;
            #pragma unroll
            for (int j = 0; j < 16; ++j) { float v = bf2f(Z[j]); ss += v * v; }
            ss += __shfl_xor(ss, 1, 64);
            ss += __shfl_xor(ss, 2, 64);
            if (q == 0) invn[p][t] = 1.0f / fmaxf(sqrtf(ss), 1e-12f);
        }
    }
    __syncthreads();

    const int wave = tid >> 6;
    const int lane = tid & 63;
    const int p    = wave >> 1;           // 0 = q, 1 = k
    const int half = wave & 1;            // token half
    const short (*Z)[72] = p ? zk : zq;

    const float s0 = qn[0], s1 = qn[1];
    const float sq2s0 = sqrtf(2.0f * fmaxf(s0, 0.0f));
    const float sq2s1 = sqrtf(2.0f * fmaxf(s1, 0.0f));
    const float sc0 = sqrtf(fmaxf(qw[0], 0.0f)) * (1.0f / 32.0f);
    const float sc1 = sqrtf(fmaxf(qw[1], 0.0f)) * (1.0f / 32.0f);

    const int lr  = lane & 15;
    const int G   = lane >> 4;
    const int kg8 = G * 8;

    f32x4 acc[2][4] = {};
    #pragma unroll
    for (int kk = 0; kk < 2; ++kk) {
        bf16x8 a[2], bh8[4], bl8[4];
        #pragma unroll
        for (int m = 0; m < 2; ++m)
            a[m] = *(const bf16x8*)&Z[half * 32 + m * 16 + lr][kk * 32 + kg8];
        #pragma unroll
        for (int n = 0; n < 4; ++n) {
            bh8[n] = *(const bf16x8*)&omh[n * 16 + lr][kk * 32 + kg8];
            bl8[n] = *(const bf16x8*)&oml[n * 16 + lr][kk * 32 + kg8];
        }
        #pragma unroll
        for (int m = 0; m < 2; ++m)
            #pragma unroll
            for (int n = 0; n < 4; ++n) {
                acc[m][n] = __builtin_amdgcn_mfma_f32_16x16x32_bf16(
                    a[m], bh8[n], acc[m][n], 0, 0, 0);
                acc[m][n] = __builtin_amdgcn_mfma_f32_16x16x32_bf16(
                    a[m], bl8[n], acc[m][n], 0, 0, 0);
            }
    }
    __syncthreads();   // all LDS reads of zq/zk done -> regions reusable

    // epilogue: features -> global; k-waves also scatter kfT into zq region
    short (*kfT)[72] = zq;                // [f][t]
    short (*vT)[72]  = zk;                // [d][t]
    {
        short* dstbase = (p ? kf : qf) + ((size_t)bh * T_ + t0) * NFEAT;
        #pragma unroll
        for (int n = 0; n < 4; ++n) {
            const int f = n * 16 + lr;
            const float s_r   = (n < 2) ? s0 : s1;
            const float sq2s  = (n < 2) ? sq2s0 : sq2s1;
            const float scale = (n < 2) ? sc0 : sc1;
            #pragma unroll
            for (int m = 0; m < 2; ++m) {
                const int tb4 = half * 32 + m * 16 + G * 4;
                #pragma unroll
                for (int j = 0; j < 4; ++j) {
                    const int t = tb4 + j;
                    const float proj = acc[m][n][j] * invn[p][t];
                    const float arg = fminf(fmaxf(proj * sq2s - s_r, -20.0f), 20.0f);
                    const float val = proj * proj * __expf(arg) * scale;
                    const short vb  = f2bf(val);
                    dstbase[(size_t)t * NFEAT + f] = vb;
                    if (p == 1) kfT[f][t] = vb;
                }
            }
        }
    }
    // v load + transpose store into zk region
    {
        const int row = tid >> 2;
        const int c0  = (tid & 3) * 16;
        const short* vrow = qkvb + ((size_t)(b * T_ + t0 + row)) * THREEC
                          + 2 * EMBED + h * HD;
        bf16x8 v0 = *(const bf16x8*)&vrow[c0], v1 = *(const bf16x8*)&vrow[c0 + 8];
        #pragma unroll
        for (int j = 0; j < 8; ++j) {
            vT[c0 + j][row]     = v0[j];
            vT[c0 + 8 + j][row] = v1[j];
        }
    }
    __syncthreads();

    // S[f][d] = sum_t kfT[f][t] * vT[d][t]; wave w owns f in [w*16, w*16+16)
    {
        bf16x8 a2[2], bv8[4][2];
        a2[0] = *(const bf16x8*)&kfT[wave * 16 + lr][kg8];
        a2[1] = *(const bf16x8*)&kfT[wave * 16 + lr][32 + kg8];
        #pragma unroll
        for (int n = 0; n < 4; ++n) {
            bv8[n][0] = *(const bf16x8*)&vT[n * 16 + lr][kg8];
            bv8[n][1] = *(const bf16x8*)&vT[n * 16 + lr][32 + kg8];
        }
        f32x4 sa[4] = {};
        #pragma unroll
        for (int n = 0; n < 4; ++n) {
            sa[n] = __builtin_amdgcn_mfma_f32_16x16x32_bf16(a2[0], bv8[n][0], sa[n], 0, 0, 0);
            sa[n] = __builtin_amdgcn_mfma_f32_16x16x32_bf16(a2[1], bv8[n][1], sa[n], 0, 0, 0);
        }
        // write cKV[chunk][d][f]: d = n*16+lr, f = wave*16 + G*4 + j (contig)
        float* base = cKV + (size_t)chunk * (NFEAT * HD);
        #pragma unroll
        for (int n = 0; n < 4; ++n) {
            float4 o; o.x = sa[n][0]; o.y = sa[n][1]; o.z = sa[n][2]; o.w = sa[n][3];
            *(float4*)&base[(n * 16 + lr) * NFEAT + wave * 16 + G * 4] = o;
        }
    }
    // cK[f] = sum_t kfT[f][t]
    {
        const int f  = tid >> 2;
        const int tq = tid & 3;
        float s = 0.0f;
        #pragma unroll
        for (int j = 0; j < 16; ++j) s += bf2f(kfT[f][tq * 16 + j]);
        s += __shfl_xor(s, 1, 64);
        s += __shfl_xor(s, 2, 64);
        if (tq == 0) cK[(size_t)chunk * NFEAT + f] = s;
    }
}

// ---------------------------------------------------------------------------
// Exclusive prefix over chunks. grid: BH_*4 blocks; depth-2 prefetch.
// ---------------------------------------------------------------------------
__global__ __launch_bounds__(256) void prefix_scan(
    float* __restrict__ cKV, float* __restrict__ cK)
{
    const int bh  = blockIdx.x >> 2;
    const int sl  = blockIdx.x & 3;
    const int tid = threadIdx.x;
    float4* base = (float4*)(cKV + (size_t)bh * NC_ * (NFEAT * HD) + sl * 1024) + tid;
    float4 n0 = base[0];
    float4 n1 = base[1024];
    float4 pref; pref.x = pref.y = pref.z = pref.w = 0.0f;
    for (int c = 0; c < NC_; ++c) {
        float4 cur = n0;
        n0 = n1;
        if (c + 2 < NC_) n1 = base[(size_t)(c + 2) * 1024];
        else { n1.x = n1.y = n1.z = n1.w = 0.0f; }
        base[(size_t)c * 1024] = pref;
        pref.x += cur.x; pref.y += cur.y; pref.z += cur.z; pref.w += cur.w;
    }
    if (sl == 0 && tid < 64) {
        float* kb = cK + (size_t)bh * NC_ * NFEAT + tid;
        float m0 = kb[0];
        float m1 = kb[64];
        float p = 0.0f;
        for (int c = 0; c < NC_; ++c) {
            float cu = m0;
            m0 = m1;
            m1 = (c + 2 < NC_) ? kb[(size_t)(c + 2) * 64] : 0.0f;
            kb[(size_t)c * 64] = p;
            p += cu;
        }
    }
}

// ---------------------------------------------------------------------------
// Intra-chunk causal attention via MFMA. 4 waves, each owns a 16-row band.
// ---------------------------------------------------------------------------
__global__ __launch_bounds__(256) void intra_mfma(
    const short* __restrict__ qf,         // [BH,T,64] bf16
    const short* __restrict__ kf,
    const short* __restrict__ qkvb,       // v region (bf16)
    const float* __restrict__ cKV,        // [chunk][d][f] prefix fp32
    const float* __restrict__ cK,         // [chunk][f] prefix fp32
    short* __restrict__ attnb)            // [B*T, EMBED] bf16
{
    __shared__ short Qs[64][72];
    __shared__ short Ks[64][72];
    __shared__ short Vt[64][72];          // V^T: [d][t]
    __shared__ short Pp[64][72];          // KVp^T: [d][f]
    __shared__ short At[64][72];          // masked A: [t][s]
    __shared__ float rs_l[64], qkp_l[64], cKp[64];

    const int tid = threadIdx.x;
    const int chunk = blockIdx.x;
    const int bh = chunk >> 6, c = chunk & 63;
    const int b = bh >> 4, h = bh & 15;
    const int t0 = c * L_;

    {
        const int row = tid >> 2;
        const int c0  = (tid & 3) * 16;
        const short* qrow = qf + ((size_t)bh * T_ + t0 + row) * NFEAT;
        const short* krow = kf + ((size_t)bh * T_ + t0 + row) * NFEAT;
        const short* vrow = qkvb + ((size_t)(b * T_ + t0 + row)) * THREEC + 2 * EMBED + h * HD;
        *(bf16x8*)&Qs[row][c0]     = *(const bf16x8*)&qrow[c0];
        *(bf16x8*)&Qs[row][c0 + 8] = *(const bf16x8*)&qrow[c0 + 8];
        *(bf16x8*)&Ks[row][c0]     = *(const bf16x8*)&krow[c0];
        *(bf16x8*)&Ks[row][c0 + 8] = *(const bf16x8*)&krow[c0 + 8];
        bf16x8 v0 = *(const bf16x8*)&vrow[c0], v1 = *(const bf16x8*)&vrow[c0 + 8];
        #pragma unroll
        for (int j = 0; j < 8; ++j) {
            Vt[c0 + j][row]     = v0[j];
            Vt[c0 + 8 + j][row] = v1[j];
        }
        const float* pbase = cKV + (size_t)chunk * (NFEAT * HD) + tid * 16;
        float4 p0 = *(const float4*)&pbase[0],  p1 = *(const float4*)&pbase[4];
        float4 p2 = *(const float4*)&pbase[8],  p3 = *(const float4*)&pbase[12];
        bf16x8 o0 = { f2bf(p0.x), f2bf(p0.y), f2bf(p0.z), f2bf(p0.w),
                      f2bf(p1.x), f2bf(p1.y), f2bf(p1.z), f2bf(p1.w) };
        bf16x8 o1 = { f2bf(p2.x), f2bf(p2.y), f2bf(p2.z), f2bf(p2.w),
                      f2bf(p3.x), f2bf(p3.y), f2bf(p3.z), f2bf(p3.w) };
        *(bf16x8*)&Pp[row][c0]     = o0;
        *(bf16x8*)&Pp[row][c0 + 8] = o1;
        if (tid < 64) cKp[tid] = cK[(size_t)chunk * NFEAT + tid];
    }
    __syncthreads();

    const int wave = tid >> 6;
    const int lane = tid & 63;
    const int lr   = lane & 15;
    const int kg   = (lane >> 4) * 8;
    const int r0   = wave * 16;

    bf16x8 aq[2];
    aq[0] = *(const bf16x8*)&Qs[r0 + lr][kg];
    aq[1] = *(const bf16x8*)&Qs[r0 + lr][32 + kg];
    f32x4 accA[4] = {};
    #pragma unroll
    for (int n = 0; n < 4; ++n) {
        accA[n] = __builtin_amdgcn_mfma_f32_16x16x32_bf16(
            aq[0], *(const bf16x8*)&Ks[n * 16 + lr][kg], accA[n], 0, 0, 0);
        accA[n] = __builtin_amdgcn_mfma_f32_16x16x32_bf16(
            aq[1], *(const bf16x8*)&Ks[n * 16 + lr][32 + kg], accA[n], 0, 0, 0);
    }
    float rsum[4] = {0.0f, 0.0f, 0.0f, 0.0f};
    #pragma unroll
    for (int n = 0; n < 4; ++n) {
        const int s = n * 16 + lr;
        #pragma unroll
        for (int j = 0; j < 4; ++j) {
            const int t = r0 + (lane >> 4) * 4 + j;
            const float a = (s <= t) ? accA[n][j] : 0.0f;
            rsum[j] += a;
            At[t][s] = f2bf(a);
        }
    }
    #pragma unroll
    for (int j = 0; j < 4; ++j) {
        rsum[j] += __shfl_xor(rsum[j], 1, 64);
        rsum[j] += __shfl_xor(rsum[j], 2, 64);
        rsum[j] += __shfl_xor(rsum[j], 4, 64);
        rsum[j] += __shfl_xor(rsum[j], 8, 64);
    }
    if (lr == 0) {
        #pragma unroll
        for (int j = 0; j < 4; ++j) rs_l[r0 + (lane >> 4) * 4 + j] = rsum[j];
    }

    {
        const int t  = tid >> 2;
        const int fq = (tid & 3) * 16;
        float s = 0.0f;
        #pragma unroll
        for (int j = 0; j < 16; ++j) s += bf2f(Qs[t][fq + j]) * cKp[fq + j];
        s += __shfl_xor(s, 1, 64);
        s += __shfl_xor(s, 2, 64);
        if ((tid & 3) == 0) qkp_l[t] = s;
    }
    __syncthreads();

    bf16x8 aa[2];
    aa[0] = *(const bf16x8*)&At[r0 + lr][kg];
    aa[1] = *(const bf16x8*)&At[r0 + lr][32 + kg];
    f32x4 acc[4] = {};
    #pragma unroll
    for (int n = 0; n < 4; ++n) {
        acc[n] = __builtin_amdgcn_mfma_f32_16x16x32_bf16(
            aa[0], *(const bf16x8*)&Vt[n * 16 + lr][kg], acc[n], 0, 0, 0);
        acc[n] = __builtin_amdgcn_mfma_f32_16x16x32_bf16(
            aa[1], *(const bf16x8*)&Vt[n * 16 + lr][32 + kg], acc[n], 0, 0, 0);
        acc[n] = __builtin_amdgcn_mfma_f32_16x16x32_bf16(
            aq[0], *(const bf16x8*)&Pp[n * 16 + lr][kg], acc[n], 0, 0, 0);
        acc[n] = __builtin_amdgcn_mfma_f32_16x16x32_bf16(
            aq[1], *(const bf16x8*)&Pp[n * 16 + lr][32 + kg], acc[n], 0, 0, 0);
    }

    float inv[4];
    #pragma unroll
    for (int j = 0; j < 4; ++j) {
        const int t = r0 + (lane >> 4) * 4 + j;
        inv[j] = 1.0f / fmaxf(rs_l[t] + qkp_l[t], 1e-6f);
    }
    #pragma unroll
    for (int n = 0; n < 4; ++n) {
        const int d = n * 16 + lr;
        #pragma unroll
        for (int j = 0; j < 4; ++j) {
            const int t = r0 + (lane >> 4) * 4 + j;
            attnb[((size_t)(b * T_ + t0 + t)) * EMBED + h * HD + d] =
                f2bf(acc[n][j] * inv[j]);
        }
    }
}

// ---------------------------------------------------------------------------
extern "C" void kernel_launch(void* const* d_in, const int* in_sizes, int n_in,
                              void* d_out, int out_size, void* d_ws, size_t ws_size,
                              hipStream_t stream)
{
    const float* x     = (const float*)d_in[0];
    const float* w_qkv = (const float*)d_in[1];
    const float* b_qkv = (const float*)d_in[2];
    const float* w_out = (const float*)d_in[3];
    const float* b_out = (const float*)d_in[4];
    const float* omega = (const float*)d_in[5];
    const float* qn    = (const float*)d_in[6];
    const float* qw    = (const float*)d_in[7];
    float* out = (float*)d_out;

    // workspace layout (shorts first, then floats)
    short* xb    = (short*)d_ws;               //  8,388,608
    short* wqb   = xb    + 8388608;            //  3,145,728
    short* wob   = wqb   + 3145728;            //  1,048,576
    short* qkvb  = wob   + 1048576;            // 25,165,824
    short* attnb = qkvb  + 25165824;           //  8,388,608
    short* omgH  = attnb + 8388608;            //     65,536
    short* omgL  = omgH  + 65536;              //     65,536
    short* qfb   = omgL  + 65536;              //  8,388,608
    short* kfb   = qfb   + 8388608;            //  8,388,608
    float* cKV   = (float*)(kfb + 8388608);    //  8,388,608 floats
    float* cK    = cKV + 8388608;              //    131,072 floats

    const int M = B_ * T_;   // 8192

    // 0. fused casts + omega prep
    prep_kernel<<<dim3((NV_ALL + 65536) / 256), 256, 0, stream>>>(
        x, w_qkv, w_out, omega, xb, wqb, wob, omgH, omgL);

    // 1. qkv = x @ w_qkv^T + b_qkv  (bf16 out) — m97-structure kernel
    gemm_bf16<1><<<dim3(THREEC / 128, M / 128), 256, 0, stream>>>(
        xb, wqb, b_qkv, nullptr, qkvb, M, THREEC, EMBED);
    // 2. features + per-chunk KV sums (fused)
    features_chunk<<<dim3(BH_ * NC_), 256, 0, stream>>>(
        qkvb, omgH, omgL, qn, qw, qfb, kfb, cKV, cK);
    // 3. exclusive prefix over chunks
    prefix_scan<<<dim3(BH_ * 4), 256, 0, stream>>>(cKV, cK);
    // 4. intra-chunk attention (MFMA) -> bf16 attn [B*T, C]
    intra_mfma<<<dim3(BH_ * NC_), 256, 0, stream>>>(qfb, kfb, qkvb, cKV, cK, attnb);
    // 5. out = attn @ w_out^T + b_out (fp32 out)
    gemm_bf16<0><<<dim3(EMBED / 128, M / 128), 256, 0, stream>>>(
        attnb, wob, b_out, out, nullptr, M, EMBED, EMBED);
}

// Round 9
// 170.371 us; speedup vs baseline: 1.4251x; 1.0020x over previous
//
#include <hip/hip_runtime.h>
#include <math.h>

#define EMBED   1024
#define THREEC  3072
#define NH      16
#define HD      64
#define NFEAT   64      // R * M = 2 * 32
#define RN      2
#define MM_     32
#define B_      2
#define T_      4096
#define L_      64      // chunk length
#define NC_     64      // T_ / L_
#define BH_     32      // B_ * NH

typedef __attribute__((ext_vector_type(8))) short bf16x8;
typedef __attribute__((ext_vector_type(4))) short bf16x4;
typedef __attribute__((ext_vector_type(4))) float f32x4;

__device__ __forceinline__ float bf2f(short s) {
    unsigned u = ((unsigned)(unsigned short)s) << 16;
    return __builtin_bit_cast(float, u);
}
__device__ __forceinline__ short f2bf(float f) {
    unsigned u = __builtin_bit_cast(unsigned, f);
    u += 0x7fff + ((u >> 16) & 1);
    return (short)(u >> 16);
}
__device__ __forceinline__ void gload16(const short* g, short* l) {
    __builtin_amdgcn_global_load_lds(
        (const __attribute__((address_space(1))) void*)g,
        (__attribute__((address_space(3))) void*)l, 16, 0, 0);
}

// ---------------------------------------------------------------------------
// Fused prep: f32->bf16 casts for x, w_qkv, w_out + omega hi/lo transpose.
// ---------------------------------------------------------------------------
#define NV_X   1048576            // 8388608 / 8
#define NV_WQ  393216             // 3145728 / 8
#define NV_WO  131072             // 1048576 / 8
#define NV_ALL (NV_X + NV_WQ + NV_WO)
__global__ __launch_bounds__(256) void prep_kernel(
    const float* __restrict__ x, const float* __restrict__ wq,
    const float* __restrict__ wo, const float* __restrict__ omega,
    short* __restrict__ xb, short* __restrict__ wqb, short* __restrict__ wob,
    short* __restrict__ omgH, short* __restrict__ omgL)
{
    int i = blockIdx.x * 256 + threadIdx.x;
    if (i < NV_ALL) {
        const float* src; short* dst; int k;
        if (i < NV_X)            { src = x;  dst = xb;  k = i; }
        else if (i < NV_X+NV_WQ) { src = wq; dst = wqb; k = i - NV_X; }
        else                     { src = wo; dst = wob; k = i - NV_X - NV_WQ; }
        const float4* p = (const float4*)src + (size_t)k * 2;
        float4 a = p[0], b = p[1];
        bf16x8 o = { f2bf(a.x), f2bf(a.y), f2bf(a.z), f2bf(a.w),
                     f2bf(b.x), f2bf(b.y), f2bf(b.z), f2bf(b.w) };
        *((bf16x8*)dst + k) = o;
    } else {
        int j = i - NV_ALL;               // 0..65535 over H*F*D
        if (j < NH * NFEAT * HD) {
            int d = j & 63;
            int f = (j >> 6) & 63;
            int h = j >> 12;
            int r = f >> 5, m = f & 31;
            float w = omega[(((size_t)(r * NH + h) * HD + d) * MM_) + m];
            short a = f2bf(w);
            omgH[j] = a;
            omgL[j] = f2bf(w - bf2f(a));
        }
    }
}

// ---------------------------------------------------------------------------
// bf16 MFMA GEMM (m97 structure): 128x128 tile, BK=32, 256 thr (4 waves,
// each 64x64), global_load_lds w16, double-buffered LDS.
// ---------------------------------------------------------------------------
template<int OUTBF>
__global__ __launch_bounds__(256) void gemm_bf16(
    const short* __restrict__ A,      // [M][K] bf16
    const short* __restrict__ W,      // [N][K] bf16
    const float* __restrict__ bias,   // [N]
    float* __restrict__ Cf, short* __restrict__ Cb,
    int M, int N, int K)
{
    __shared__ short lA[2][128 * 32];
    __shared__ short lB[2][128 * 32];
    const int tid  = threadIdx.x;
    const int bm   = blockIdx.y * 128;
    const int bn   = blockIdx.x * 128;
    const int lane = tid & 63;
    const int wave = tid >> 6;
    const int row0 = (wave >> 1) * 64;
    const int col0 = (wave & 1) * 64;
    const int lr   = lane & 15;
    const int kg8  = (lane >> 4) * 8;

    f32x4 acc[4][4] = {};

#define STAGE(buf, k0)                                                        \
    {                                                                         \
        _Pragma("unroll")                                                     \
        for (int i = 0; i < 2; ++i) {                                         \
            int idx = i * 256 + tid;                                          \
            int row = idx >> 2, kq = (idx & 3) * 8;                           \
            gload16(&A[(size_t)(bm + row) * K + (k0) + kq], &lA[buf][idx * 8]); \
            gload16(&W[(size_t)(bn + row) * K + (k0) + kq], &lB[buf][idx * 8]); \
        }                                                                     \
    }

    const int KT = K >> 5;
    STAGE(0, 0);
    __syncthreads();
    int cur = 0;
    for (int kt = 0; kt < KT; ++kt) {
        if (kt + 1 < KT) STAGE(cur ^ 1, (kt + 1) * 32);
        const short* As = lA[cur];
        const short* Bs = lB[cur];
        bf16x8 af[4], bfr[4];
        #pragma unroll
        for (int m = 0; m < 4; ++m)
            af[m] = *(const bf16x8*)&As[(row0 + m * 16 + lr) * 32 + kg8];
        #pragma unroll
        for (int n = 0; n < 4; ++n)
            bfr[n] = *(const bf16x8*)&Bs[(col0 + n * 16 + lr) * 32 + kg8];
        #pragma unroll
        for (int m = 0; m < 4; ++m)
            #pragma unroll
            for (int n = 0; n < 4; ++n)
                acc[m][n] = __builtin_amdgcn_mfma_f32_16x16x32_bf16(
                    af[m], bfr[n], acc[m][n], 0, 0, 0);
        __syncthreads();
        cur ^= 1;
    }
#undef STAGE

    #pragma unroll
    for (int n = 0; n < 4; ++n) {
        const int col = bn + col0 + n * 16 + (lane & 15);
        const float bvv = bias[col];
        #pragma unroll
        for (int m = 0; m < 4; ++m) {
            const int rbase = bm + row0 + m * 16 + (lane >> 4) * 4;
            #pragma unroll
            for (int j = 0; j < 4; ++j) {
                const float v = acc[m][n][j] + bvv;
                if (OUTBF) Cb[(size_t)(rbase + j) * N + col] = f2bf(v);
                else       Cf[(size_t)(rbase + j) * N + col] = v;
            }
        }
    }
}

// ---------------------------------------------------------------------------
// Fused: feature map + per-chunk KV sums + INTRA-chunk attention local part.
// One block = one (bh, chunk of 64 tokens). LDS region reuse:
//   zq: z_q tile            -> kfT [f][t]
//   zk: z_k tile            -> vT  [d][t]
//   omh: omega hi           -> Q row-major [t][f]
//   oml: omega lo           -> K row-major [t][f] -> masked At [t][s]
// Outputs: qf (global), ctx_local=A@V (bf16), rowsum (f32),
//          cKV chunk sums S^T (bf16), cK sums (f32). kf never hits global.
// ---------------------------------------------------------------------------
__global__ __launch_bounds__(256) void feat_fused(
    const short* __restrict__ qkvb,       // [B, T, 3C] bf16
    const short* __restrict__ omgH,       // [H][64f][64d] bf16 (hi)
    const short* __restrict__ omgL,       // [H][64f][64d] bf16 (lo)
    const float* __restrict__ qn,
    const float* __restrict__ qw,
    short* __restrict__ qf,               // [BH, T, 64] bf16
    short* __restrict__ ctxb,             // [BH, T, 64] bf16 local ctx
    float* __restrict__ rs_g,             // [BH, T] f32 rowsum
    short* __restrict__ cKVb,             // [BH*NC, 64d, 64f] bf16 S^T
    float* __restrict__ cK)               // [BH*NC, 64] f32
{
    __shared__ short zq[64][72];
    __shared__ short zk[64][72];
    __shared__ short omh[64][72];
    __shared__ short oml[64][72];
    __shared__ float invn[2][64];
    __shared__ float rs_l[64];

    const int tid   = threadIdx.x;
    const int chunk = blockIdx.x;         // bh*64 + c
    const int bh    = chunk >> 6;
    const int c     = chunk & 63;
    const int b     = bh >> 4, h = bh & 15;
    const int t0    = c * 64;

    // phase 1: load tiles
    {
        const int row = tid >> 2;
        const int c0  = (tid & 3) * 16;
        const size_t zbase = ((size_t)(b * T_ + t0 + row)) * THREEC + h * HD + c0;
        const size_t obase = ((size_t)h * NFEAT + row) * HD + c0;
        *(bf16x8*)&zq[row][c0]      = *(const bf16x8*)&qkvb[zbase];
        *(bf16x8*)&zq[row][c0 + 8]  = *(const bf16x8*)&qkvb[zbase + 8];
        *(bf16x8*)&zk[row][c0]      = *(const bf16x8*)&qkvb[zbase + EMBED];
        *(bf16x8*)&zk[row][c0 + 8]  = *(const bf16x8*)&qkvb[zbase + EMBED + 8];
        *(bf16x8*)&omh[row][c0]     = *(const bf16x8*)&omgH[obase];
        *(bf16x8*)&omh[row][c0 + 8] = *(const bf16x8*)&omgH[obase + 8];
        *(bf16x8*)&oml[row][c0]     = *(const bf16x8*)&omgL[obase];
        *(bf16x8*)&oml[row][c0 + 8] = *(const bf16x8*)&omgL[obase + 8];
    }
    __syncthreads();

    // phase 2: per-token inverse norms
    {
        const int t = tid >> 2;
        const int q = tid & 3;
        #pragma unroll
        for (int p = 0; p < 2; ++p) {
            const short* Z = p ? &zk[t][q * 16] : &zq[t][q * 16];
            float ss = 0.0f;
            #pragma unroll
            for (int j = 0; j < 16; ++j) { float v = bf2f(Z[j]); ss += v * v; }
            ss += __shfl_xor(ss, 1, 64);
            ss += __shfl_xor(ss, 2, 64);
            if (q == 0) invn[p][t] = 1.0f / fmaxf(sqrtf(ss), 1e-12f);
        }
    }
    __syncthreads();

    const int wave = tid >> 6;
    const int lane = tid & 63;
    const int p    = wave >> 1;           // 0 = q, 1 = k
    const int half = wave & 1;            // token half
    const short (*Z)[72] = p ? zk : zq;

    const float s0 = qn[0], s1 = qn[1];
    const float sq2s0 = sqrtf(2.0f * fmaxf(s0, 0.0f));
    const float sq2s1 = sqrtf(2.0f * fmaxf(s1, 0.0f));
    const float sc0 = sqrtf(fmaxf(qw[0], 0.0f)) * (1.0f / 32.0f);
    const float sc1 = sqrtf(fmaxf(qw[1], 0.0f)) * (1.0f / 32.0f);

    const int lr  = lane & 15;
    const int G   = lane >> 4;
    const int kg8 = G * 8;

    // phase 3: projection MFMAs
    f32x4 acc[2][4] = {};
    #pragma unroll
    for (int kk = 0; kk < 2; ++kk) {
        bf16x8 a[2], bh8[4], bl8[4];
        #pragma unroll
        for (int m = 0; m < 2; ++m)
            a[m] = *(const bf16x8*)&Z[half * 32 + m * 16 + lr][kk * 32 + kg8];
        #pragma unroll
        for (int n = 0; n < 4; ++n) {
            bh8[n] = *(const bf16x8*)&omh[n * 16 + lr][kk * 32 + kg8];
            bl8[n] = *(const bf16x8*)&oml[n * 16 + lr][kk * 32 + kg8];
        }
        #pragma unroll
        for (int m = 0; m < 2; ++m)
            #pragma unroll
            for (int n = 0; n < 4; ++n) {
                acc[m][n] = __builtin_amdgcn_mfma_f32_16x16x32_bf16(
                    a[m], bh8[n], acc[m][n], 0, 0, 0);
                acc[m][n] = __builtin_amdgcn_mfma_f32_16x16x32_bf16(
                    a[m], bl8[n], acc[m][n], 0, 0, 0);
            }
    }
    __syncthreads();   // all LDS reads done -> all 4 regions reusable

    // phase 4: feature transform -> LDS scatters (Qrm, Krm, kfT) + vT
    short (*kfT)[72] = zq;                // [f][t]
    short (*vT)[72]  = zk;                // [d][t]
    short (*Qrm)[72] = omh;               // [t][f]
    short (*Krm)[72] = oml;               // [t][f]
    {
        #pragma unroll
        for (int n = 0; n < 4; ++n) {
            const int f = n * 16 + lr;
            const float s_r   = (n < 2) ? s0 : s1;
            const float sq2s  = (n < 2) ? sq2s0 : sq2s1;
            const float scale = (n < 2) ? sc0 : sc1;
            #pragma unroll
            for (int m = 0; m < 2; ++m) {
                const int tb4 = half * 32 + m * 16 + G * 4;
                #pragma unroll
                for (int j = 0; j < 4; ++j) {
                    const int t = tb4 + j;
                    const float proj = acc[m][n][j] * invn[p][t];
                    const float arg = fminf(fmaxf(proj * sq2s - s_r, -20.0f), 20.0f);
                    const float val = proj * proj * __expf(arg) * scale;
                    const short vb  = f2bf(val);
                    if (p == 0) { Qrm[t][f] = vb; }
                    else        { kfT[f][t] = vb; Krm[t][f] = vb; }
                }
            }
        }
    }
    {   // v load + transpose scatter
        const int row = tid >> 2;
        const int c0  = (tid & 3) * 16;
        const short* vrow = qkvb + ((size_t)(b * T_ + t0 + row)) * THREEC
                          + 2 * EMBED + h * HD;
        bf16x8 v0 = *(const bf16x8*)&vrow[c0], v1 = *(const bf16x8*)&vrow[c0 + 8];
        #pragma unroll
        for (int j = 0; j < 8; ++j) {
            vT[c0 + j][row]     = v0[j];
            vT[c0 + 8 + j][row] = v1[j];
        }
    }
    __syncthreads();

    const int r0 = wave * 16;

    // phase 5a: qf -> global (coalesced from Qrm)
    {
        const int row = tid >> 2;
        const int c0  = (tid & 3) * 16;
        short* dst = qf + ((size_t)bh * T_ + t0 + row) * NFEAT;
        *(bf16x8*)&dst[c0]     = *(const bf16x8*)&Qrm[row][c0];
        *(bf16x8*)&dst[c0 + 8] = *(const bf16x8*)&Qrm[row][c0 + 8];
    }
    // phase 5b: A = Qf @ Kf^T (wave band r0..r0+15)
    bf16x8 aqq[2];
    aqq[0] = *(const bf16x8*)&Qrm[r0 + lr][kg8];
    aqq[1] = *(const bf16x8*)&Qrm[r0 + lr][32 + kg8];
    f32x4 accA[4] = {};
    #pragma unroll
    for (int n = 0; n < 4; ++n) {
        accA[n] = __builtin_amdgcn_mfma_f32_16x16x32_bf16(
            aqq[0], *(const bf16x8*)&Krm[n * 16 + lr][kg8], accA[n], 0, 0, 0);
        accA[n] = __builtin_amdgcn_mfma_f32_16x16x32_bf16(
            aqq[1], *(const bf16x8*)&Krm[n * 16 + lr][32 + kg8], accA[n], 0, 0, 0);
    }
    // phase 5c: masked rowsum
    {
        float rsum[4] = {0.0f, 0.0f, 0.0f, 0.0f};
        #pragma unroll
        for (int n = 0; n < 4; ++n) {
            const int s = n * 16 + lr;
            #pragma unroll
            for (int j = 0; j < 4; ++j) {
                const int t = r0 + G * 4 + j;
                if (s <= t) rsum[j] += accA[n][j];
            }
        }
        #pragma unroll
        for (int j = 0; j < 4; ++j) {
            rsum[j] += __shfl_xor(rsum[j], 1, 64);
            rsum[j] += __shfl_xor(rsum[j], 2, 64);
            rsum[j] += __shfl_xor(rsum[j], 4, 64);
            rsum[j] += __shfl_xor(rsum[j], 8, 64);
        }
        if (lr == 0) {
            #pragma unroll
            for (int j = 0; j < 4; ++j) rs_l[r0 + G * 4 + j] = rsum[j];
        }
    }
    // phase 5d: S[f][d] = kfT @ vT^T -> cKVb bf16 [chunk][d][f]
    {
        bf16x8 a2[2];
        a2[0] = *(const bf16x8*)&kfT[wave * 16 + lr][kg8];
        a2[1] = *(const bf16x8*)&kfT[wave * 16 + lr][32 + kg8];
        f32x4 sa[4] = {};
        #pragma unroll
        for (int n = 0; n < 4; ++n) {
            sa[n] = __builtin_amdgcn_mfma_f32_16x16x32_bf16(
                a2[0], *(const bf16x8*)&vT[n * 16 + lr][kg8], sa[n], 0, 0, 0);
            sa[n] = __builtin_amdgcn_mfma_f32_16x16x32_bf16(
                a2[1], *(const bf16x8*)&vT[n * 16 + lr][32 + kg8], sa[n], 0, 0, 0);
        }
        short* basep = cKVb + (size_t)chunk * (NFEAT * HD);
        #pragma unroll
        for (int n = 0; n < 4; ++n) {
            bf16x4 o = { f2bf(sa[n][0]), f2bf(sa[n][1]),
                         f2bf(sa[n][2]), f2bf(sa[n][3]) };
            *(bf16x4*)&basep[(n * 16 + lr) * NFEAT + wave * 16 + G * 4] = o;
        }
    }
    // phase 5e: cK[f]
    {
        const int f  = tid >> 2;
        const int tq = tid & 3;
        float s = 0.0f;
        #pragma unroll
        for (int j = 0; j < 16; ++j) s += bf2f(kfT[f][tq * 16 + j]);
        s += __shfl_xor(s, 1, 64);
        s += __shfl_xor(s, 2, 64);
        if (tq == 0) cK[(size_t)chunk * NFEAT + f] = s;
    }
    __syncthreads();   // Krm reads done -> oml reusable as At

    // phase 6: masked A -> At [t][s] (over oml)
    short (*At)[72] = oml;
    #pragma unroll
    for (int n = 0; n < 4; ++n) {
        const int s = n * 16 + lr;
        #pragma unroll
        for (int j = 0; j < 4; ++j) {
            const int t = r0 + G * 4 + j;
            At[t][s] = f2bf((s <= t) ? accA[n][j] : 0.0f);
        }
    }
    __syncthreads();

    // phase 7: ctx_local = A @ V -> global; rowsum -> global
    {
        bf16x8 aa[2];
        aa[0] = *(const bf16x8*)&At[r0 + lr][kg8];
        aa[1] = *(const bf16x8*)&At[r0 + lr][32 + kg8];
        f32x4 a2[4] = {};
        #pragma unroll
        for (int n = 0; n < 4; ++n) {
            a2[n] = __builtin_amdgcn_mfma_f32_16x16x32_bf16(
                aa[0], *(const bf16x8*)&vT[n * 16 + lr][kg8], a2[n], 0, 0, 0);
            a2[n] = __builtin_amdgcn_mfma_f32_16x16x32_bf16(
                aa[1], *(const bf16x8*)&vT[n * 16 + lr][32 + kg8], a2[n], 0, 0, 0);
        }
        #pragma unroll
        for (int n = 0; n < 4; ++n) {
            const int d = n * 16 + lr;
            #pragma unroll
            for (int j = 0; j < 4; ++j) {
                const int t = r0 + G * 4 + j;
                ctxb[((size_t)bh * T_ + t0 + t) * NFEAT + d] = f2bf(a2[n][j]);
            }
        }
    }
    if (tid < 64) rs_g[(size_t)bh * T_ + t0 + tid] = rs_l[tid];
}

// ---------------------------------------------------------------------------
// Exclusive prefix over chunks, bf16 cKV (fp32 accumulators).
// grid: BH_*4 blocks; each thread owns 4 elements; depth-2 prefetch.
// ---------------------------------------------------------------------------
__global__ __launch_bounds__(256) void prefix_scan(
    short* __restrict__ cKVb, float* __restrict__ cK)
{
    const int bh  = blockIdx.x >> 2;
    const int sl  = blockIdx.x & 3;
    const int tid = threadIdx.x;
    short* base = cKVb + (size_t)bh * NC_ * (NFEAT * HD) + sl * 1024 + tid * 4;
    bf16x4 n0 = *(const bf16x4*)(base);
    bf16x4 n1 = *(const bf16x4*)(base + 4096);
    float pref[4] = {0.0f, 0.0f, 0.0f, 0.0f};
    for (int c = 0; c < NC_; ++c) {
        bf16x4 cur = n0;
        n0 = n1;
        if (c + 2 < NC_) n1 = *(const bf16x4*)(base + (size_t)(c + 2) * 4096);
        else { n1[0] = 0; n1[1] = 0; n1[2] = 0; n1[3] = 0; }
        bf16x4 o = { f2bf(pref[0]), f2bf(pref[1]), f2bf(pref[2]), f2bf(pref[3]) };
        *(bf16x4*)(base + (size_t)c * 4096) = o;
        pref[0] += bf2f(cur[0]); pref[1] += bf2f(cur[1]);
        pref[2] += bf2f(cur[2]); pref[3] += bf2f(cur[3]);
    }
    if (sl == 0 && tid < 64) {
        float* kb = cK + (size_t)bh * NC_ * NFEAT + tid;
        float m0 = kb[0];
        float m1 = kb[64];
        float p = 0.0f;
        for (int c = 0; c < NC_; ++c) {
            float cu = m0;
            m0 = m1;
            m1 = (c + 2 < NC_) ? kb[(size_t)(c + 2) * 64] : 0.0f;
            kb[(size_t)c * 64] = p;
            p += cu;
        }
    }
}

// ---------------------------------------------------------------------------
// Inter-chunk term + finalize: out = (ctx_local + Qf@KVp^T) / den -> attnb.
// ---------------------------------------------------------------------------
__global__ __launch_bounds__(256) void inter_attn(
    const short* __restrict__ qf,         // [BH,T,64] bf16
    const short* __restrict__ ctxb,       // [BH,T,64] bf16
    const float* __restrict__ rs_g,       // [BH,T]
    const short* __restrict__ cKVp,       // [chunk][d][f] prefix bf16
    const float* __restrict__ cKp_g,      // [chunk][f] prefix f32
    short* __restrict__ attnb)            // [B*T, EMBED] bf16
{
    __shared__ short Q[64][72];
    __shared__ short Pp[64][72];
    __shared__ float cKp[64], rs[64], qkp_l[64];

    const int tid = threadIdx.x;
    const int chunk = blockIdx.x;
    const int bh = chunk >> 6, c = chunk & 63;
    const int b = bh >> 4, h = bh & 15;
    const int t0 = c * 64;

    {
        const int row = tid >> 2;
        const int c0  = (tid & 3) * 16;
        const short* qrow = qf   + ((size_t)bh * T_ + t0 + row) * NFEAT;
        const short* prow = cKVp + (size_t)chunk * (NFEAT * HD) + row * NFEAT;
        *(bf16x8*)&Q[row][c0]      = *(const bf16x8*)&qrow[c0];
        *(bf16x8*)&Q[row][c0 + 8]  = *(const bf16x8*)&qrow[c0 + 8];
        *(bf16x8*)&Pp[row][c0]     = *(const bf16x8*)&prow[c0];
        *(bf16x8*)&Pp[row][c0 + 8] = *(const bf16x8*)&prow[c0 + 8];
        if (tid < 64) {
            cKp[tid] = cKp_g[(size_t)chunk * NFEAT + tid];
            rs[tid]  = rs_g[(size_t)bh * T_ + t0 + tid];
        }
    }
    __syncthreads();

    // qkp[t] = Q[t] . cKp
    {
        const int t  = tid >> 2;
        const int fq = (tid & 3) * 16;
        float s = 0.0f;
        #pragma unroll
        for (int j = 0; j < 16; ++j) s += bf2f(Q[t][fq + j]) * cKp[fq + j];
        s += __shfl_xor(s, 1, 64);
        s += __shfl_xor(s, 2, 64);
        if ((tid & 3) == 0) qkp_l[t] = s;
    }

    const int wave = tid >> 6;
    const int lane = tid & 63;
    const int lr = lane & 15;
    const int G  = lane >> 4;
    const int kg = G * 8;
    const int r0 = wave * 16;

    bf16x8 aq[2];
    aq[0] = *(const bf16x8*)&Q[r0 + lr][kg];
    aq[1] = *(const bf16x8*)&Q[r0 + lr][32 + kg];
    f32x4 acc[4] = {};
    #pragma unroll
    for (int n = 0; n < 4; ++n) {
        acc[n] = __builtin_amdgcn_mfma_f32_16x16x32_bf16(
            aq[0], *(const bf16x8*)&Pp[n * 16 + lr][kg], acc[n], 0, 0, 0);
        acc[n] = __builtin_amdgcn_mfma_f32_16x16x32_bf16(
            aq[1], *(const bf16x8*)&Pp[n * 16 + lr][32 + kg], acc[n], 0, 0, 0);
    }
    __syncthreads();   // qkp_l visible

    float inv[4];
    #pragma unroll
    for (int j = 0; j < 4; ++j) {
        const int t = r0 + G * 4 + j;
        inv[j] = 1.0f / fmaxf(rs[t] + qkp_l[t], 1e-6f);
    }
    #pragma unroll
    for (int n = 0; n < 4; ++n) {
        const int d = n * 16 + lr;
        #pragma unroll
        for (int j = 0; j < 4; ++j) {
            const int t = r0 + G * 4 + j;
            const float ctx = bf2f(ctxb[((size_t)bh * T_ + t0 + t) * NFEAT + d]);
            attnb[((size_t)(b * T_ + t0 + t)) * EMBED + h * HD + d] =
                f2bf((ctx + acc[n][j]) * inv[j]);
        }
    }
}

// ---------------------------------------------------------------------------
extern "C" void kernel_launch(void* const* d_in, const int* in_sizes, int n_in,
                              void* d_out, int out_size, void* d_ws, size_t ws_size,
                              hipStream_t stream)
{
    const float* x     = (const float*)d_in[0];
    const float* w_qkv = (const float*)d_in[1];
    const float* b_qkv = (const float*)d_in[2];
    const float* w_out = (const float*)d_in[3];
    const float* b_out = (const float*)d_in[4];
    const float* omega = (const float*)d_in[5];
    const float* qn    = (const float*)d_in[6];
    const float* qw    = (const float*)d_in[7];
    float* out = (float*)d_out;

    // workspace layout
    short* xb    = (short*)d_ws;               //  8,388,608
    short* wqb   = xb    + 8388608;            //  3,145,728
    short* wob   = wqb   + 3145728;            //  1,048,576
    short* qkvb  = wob   + 1048576;            // 25,165,824
    short* attnb = qkvb  + 25165824;           //  8,388,608
    short* omgH  = attnb + 8388608;            //     65,536
    short* omgL  = omgH  + 65536;              //     65,536
    short* qfb   = omgL  + 65536;              //  8,388,608
    short* ctxb  = qfb   + 8388608;            //  8,388,608
    short* cKVb  = ctxb  + 8388608;            //  8,388,608
    float* cK    = (float*)(cKVb + 8388608);   //    131,072 floats
    float* rs_g  = cK + 131072;                //    131,072 floats

    const int M = B_ * T_;   // 8192

    // 0. fused casts + omega prep
    prep_kernel<<<dim3((NV_ALL + 65536) / 256), 256, 0, stream>>>(
        x, w_qkv, w_out, omega, xb, wqb, wob, omgH, omgL);

    // 1. qkv = x @ w_qkv^T + b_qkv  (bf16 out)
    gemm_bf16<1><<<dim3(THREEC / 128, M / 128), 256, 0, stream>>>(
        xb, wqb, b_qkv, nullptr, qkvb, M, THREEC, EMBED);
    // 2. features + chunk sums + intra-chunk local attention (fused)
    feat_fused<<<dim3(BH_ * NC_), 256, 0, stream>>>(
        qkvb, omgH, omgL, qn, qw, qfb, ctxb, rs_g, cKVb, cK);
    // 3. exclusive prefix over chunks (bf16)
    prefix_scan<<<dim3(BH_ * 4), 256, 0, stream>>>(cKVb, cK);
    // 4. inter-chunk term + finalize -> bf16 attn [B*T, C]
    inter_attn<<<dim3(BH_ * NC_), 256, 0, stream>>>(
        qfb, ctxb, rs_g, cKVb, cK, attnb);
    // 5. out = attn @ w_out^T + b_out (fp32 out)
    gemm_bf16<0><<<dim3(EMBED / 128, M / 128), 256, 0, stream>>>(
        attnb, wob, b_out, out, nullptr, M, EMBED, EMBED);
}

// Round 10
// 168.970 us; speedup vs baseline: 1.4369x; 1.0083x over previous
//
#include <hip/hip_runtime.h>
#include <math.h>

#define EMBED   1024
#define THREEC  3072
#define NH      16
#define HD      64
#define NFEAT   64      // R * M = 2 * 32
#define RN      2
#define MM_     32
#define B_      2
#define T_      4096
#define L_      64      // chunk length
#define NC_     64      // T_ / L_
#define BH_     32      // B_ * NH

typedef __attribute__((ext_vector_type(8))) short bf16x8;
typedef __attribute__((ext_vector_type(4))) short bf16x4;
typedef __attribute__((ext_vector_type(4))) float f32x4;

__device__ __forceinline__ float bf2f(short s) {
    unsigned u = ((unsigned)(unsigned short)s) << 16;
    return __builtin_bit_cast(float, u);
}
__device__ __forceinline__ short f2bf(float f) {
    unsigned u = __builtin_bit_cast(unsigned, f);
    u += 0x7fff + ((u >> 16) & 1);
    return (short)(u >> 16);
}
__device__ __forceinline__ void gload16(const short* g, short* l) {
    __builtin_amdgcn_global_load_lds(
        (const __attribute__((address_space(1))) void*)g,
        (__attribute__((address_space(3))) void*)l, 16, 0, 0);
}

// ---------------------------------------------------------------------------
// Fused prep: f32->bf16 casts for x, w_qkv, w_out + omega hi/lo transpose.
// ---------------------------------------------------------------------------
#define NV_X   1048576            // 8388608 / 8
#define NV_WQ  393216             // 3145728 / 8
#define NV_WO  131072             // 1048576 / 8
#define NV_ALL (NV_X + NV_WQ + NV_WO)
__global__ __launch_bounds__(256) void prep_kernel(
    const float* __restrict__ x, const float* __restrict__ wq,
    const float* __restrict__ wo, const float* __restrict__ omega,
    short* __restrict__ xb, short* __restrict__ wqb, short* __restrict__ wob,
    short* __restrict__ omgH, short* __restrict__ omgL)
{
    int i = blockIdx.x * 256 + threadIdx.x;
    if (i < NV_ALL) {
        const float* src; short* dst; int k;
        if (i < NV_X)            { src = x;  dst = xb;  k = i; }
        else if (i < NV_X+NV_WQ) { src = wq; dst = wqb; k = i - NV_X; }
        else                     { src = wo; dst = wob; k = i - NV_X - NV_WQ; }
        const float4* p = (const float4*)src + (size_t)k * 2;
        float4 a = p[0], b = p[1];
        bf16x8 o = { f2bf(a.x), f2bf(a.y), f2bf(a.z), f2bf(a.w),
                     f2bf(b.x), f2bf(b.y), f2bf(b.z), f2bf(b.w) };
        *((bf16x8*)dst + k) = o;
    } else {
        int j = i - NV_ALL;               // 0..65535 over H*F*D
        if (j < NH * NFEAT * HD) {
            int d = j & 63;
            int f = (j >> 6) & 63;
            int h = j >> 12;
            int r = f >> 5, m = f & 31;
            float w = omega[(((size_t)(r * NH + h) * HD + d) * MM_) + m];
            short a = f2bf(w);
            omgH[j] = a;
            omgL[j] = f2bf(w - bf2f(a));
        }
    }
}

// ---------------------------------------------------------------------------
// bf16 MFMA GEMM (m97 structure), 1D grid + XCD-aware M-stripe swizzle.
// ---------------------------------------------------------------------------
template<int OUTBF>
__global__ __launch_bounds__(256) void gemm_bf16(
    const short* __restrict__ A,      // [M][K] bf16
    const short* __restrict__ W,      // [N][K] bf16
    const float* __restrict__ bias,   // [N]
    float* __restrict__ Cf, short* __restrict__ Cb,
    int M, int N, int K)
{
    __shared__ short lA[2][128 * 32];
    __shared__ short lB[2][128 * 32];
    const int tid  = threadIdx.x;
    const int nbn  = N >> 7;
    const int cpx  = gridDim.x >> 3;
    const int swz  = (blockIdx.x & 7) * cpx + (blockIdx.x >> 3);
    const int bm   = (swz / nbn) << 7;
    const int bn   = (swz % nbn) << 7;
    const int lane = tid & 63;
    const int wave = tid >> 6;
    const int row0 = (wave >> 1) * 64;
    const int col0 = (wave & 1) * 64;
    const int lr   = lane & 15;
    const int kg8  = (lane >> 4) * 8;

    f32x4 acc[4][4] = {};

#define STAGE(buf, k0)                                                        \
    {                                                                         \
        _Pragma("unroll")                                                     \
        for (int i = 0; i < 2; ++i) {                                         \
            int idx = i * 256 + tid;                                          \
            int row = idx >> 2, kq = (idx & 3) * 8;                           \
            gload16(&A[(size_t)(bm + row) * K + (k0) + kq], &lA[buf][idx * 8]); \
            gload16(&W[(size_t)(bn + row) * K + (k0) + kq], &lB[buf][idx * 8]); \
        }                                                                     \
    }

    const int KT = K >> 5;
    STAGE(0, 0);
    __syncthreads();
    int cur = 0;
    for (int kt = 0; kt < KT; ++kt) {
        if (kt + 1 < KT) STAGE(cur ^ 1, (kt + 1) * 32);
        const short* As = lA[cur];
        const short* Bs = lB[cur];
        bf16x8 af[4], bfr[4];
        #pragma unroll
        for (int m = 0; m < 4; ++m)
            af[m] = *(const bf16x8*)&As[(row0 + m * 16 + lr) * 32 + kg8];
        #pragma unroll
        for (int n = 0; n < 4; ++n)
            bfr[n] = *(const bf16x8*)&Bs[(col0 + n * 16 + lr) * 32 + kg8];
        #pragma unroll
        for (int m = 0; m < 4; ++m)
            #pragma unroll
            for (int n = 0; n < 4; ++n)
                acc[m][n] = __builtin_amdgcn_mfma_f32_16x16x32_bf16(
                    af[m], bfr[n], acc[m][n], 0, 0, 0);
        __syncthreads();
        cur ^= 1;
    }
#undef STAGE

    #pragma unroll
    for (int n = 0; n < 4; ++n) {
        const int col = bn + col0 + n * 16 + (lane & 15);
        const float bvv = bias[col];
        #pragma unroll
        for (int m = 0; m < 4; ++m) {
            const int rbase = bm + row0 + m * 16 + (lane >> 4) * 4;
            #pragma unroll
            for (int j = 0; j < 4; ++j) {
                const float v = acc[m][n][j] + bvv;
                if (OUTBF) Cb[(size_t)(rbase + j) * N + col] = f2bf(v);
                else       Cf[(size_t)(rbase + j) * N + col] = v;
            }
        }
    }
}

// ---------------------------------------------------------------------------
// Fused: feature map + per-chunk KV sums + INTRA-chunk attention local part.
// LDS reuse: zq->kfT, zk->vT, omh->Qrm, oml->Krm->At->ctx-rows.
// ---------------------------------------------------------------------------
__global__ __launch_bounds__(256) void feat_fused(
    const short* __restrict__ qkvb,
    const short* __restrict__ omgH,
    const short* __restrict__ omgL,
    const float* __restrict__ qn,
    const float* __restrict__ qw,
    short* __restrict__ qf,
    short* __restrict__ ctxb,
    float* __restrict__ rs_g,
    short* __restrict__ cKVb,
    float* __restrict__ cK)
{
    __shared__ short zq[64][72];
    __shared__ short zk[64][72];
    __shared__ short omh[64][72];
    __shared__ short oml[64][72];
    __shared__ float invn[2][64];
    __shared__ float rs_l[64];

    const int tid   = threadIdx.x;
    const int chunk = blockIdx.x;
    const int bh    = chunk >> 6;
    const int c     = chunk & 63;
    const int b     = bh >> 4, h = bh & 15;
    const int t0    = c * 64;

    {
        const int row = tid >> 2;
        const int c0  = (tid & 3) * 16;
        const size_t zbase = ((size_t)(b * T_ + t0 + row)) * THREEC + h * HD + c0;
        const size_t obase = ((size_t)h * NFEAT + row) * HD + c0;
        *(bf16x8*)&zq[row][c0]      = *(const bf16x8*)&qkvb[zbase];
        *(bf16x8*)&zq[row][c0 + 8]  = *(const bf16x8*)&qkvb[zbase + 8];
        *(bf16x8*)&zk[row][c0]      = *(const bf16x8*)&qkvb[zbase + EMBED];
        *(bf16x8*)&zk[row][c0 + 8]  = *(const bf16x8*)&qkvb[zbase + EMBED + 8];
        *(bf16x8*)&omh[row][c0]     = *(const bf16x8*)&omgH[obase];
        *(bf16x8*)&omh[row][c0 + 8] = *(const bf16x8*)&omgH[obase + 8];
        *(bf16x8*)&oml[row][c0]     = *(const bf16x8*)&omgL[obase];
        *(bf16x8*)&oml[row][c0 + 8] = *(const bf16x8*)&omgL[obase + 8];
    }
    __syncthreads();

    {
        const int t = tid >> 2;
        const int q = tid & 3;
        #pragma unroll
        for (int p = 0; p < 2; ++p) {
            const short* Z = p ? &zk[t][q * 16] : &zq[t][q * 16];
            float ss = 0.0f;
            #pragma unroll
            for (int j = 0; j < 16; ++j) { float v = bf2f(Z[j]); ss += v * v; }
            ss += __shfl_xor(ss, 1, 64);
            ss += __shfl_xor(ss, 2, 64);
            if (q == 0) invn[p][t] = 1.0f / fmaxf(sqrtf(ss), 1e-12f);
        }
    }
    __syncthreads();

    const int wave = tid >> 6;
    const int lane = tid & 63;
    const int p    = wave >> 1;
    const int half = wave & 1;
    const short (*Z)[72] = p ? zk : zq;

    const float s0 = qn[0], s1 = qn[1];
    const float sq2s0 = sqrtf(2.0f * fmaxf(s0, 0.0f));
    const float sq2s1 = sqrtf(2.0f * fmaxf(s1, 0.0f));
    const float sc0 = sqrtf(fmaxf(qw[0], 0.0f)) * (1.0f / 32.0f);
    const float sc1 = sqrtf(fmaxf(qw[1], 0.0f)) * (1.0f / 32.0f);

    const int lr  = lane & 15;
    const int G   = lane >> 4;
    const int kg8 = G * 8;

    f32x4 acc[2][4] = {};
    #pragma unroll
    for (int kk = 0; kk < 2; ++kk) {
        bf16x8 a[2], bh8[4], bl8[4];
        #pragma unroll
        for (int m = 0; m < 2; ++m)
            a[m] = *(const bf16x8*)&Z[half * 32 + m * 16 + lr][kk * 32 + kg8];
        #pragma unroll
        for (int n = 0; n < 4; ++n) {
            bh8[n] = *(const bf16x8*)&omh[n * 16 + lr][kk * 32 + kg8];
            bl8[n] = *(const bf16x8*)&oml[n * 16 + lr][kk * 32 + kg8];
        }
        #pragma unroll
        for (int m = 0; m < 2; ++m)
            #pragma unroll
            for (int n = 0; n < 4; ++n) {
                acc[m][n] = __builtin_amdgcn_mfma_f32_16x16x32_bf16(
                    a[m], bh8[n], acc[m][n], 0, 0, 0);
                acc[m][n] = __builtin_amdgcn_mfma_f32_16x16x32_bf16(
                    a[m], bl8[n], acc[m][n], 0, 0, 0);
            }
    }
    __syncthreads();

    short (*kfT)[72] = zq;
    short (*vT)[72]  = zk;
    short (*Qrm)[72] = omh;
    short (*Krm)[72] = oml;
    {
        #pragma unroll
        for (int n = 0; n < 4; ++n) {
            const int f = n * 16 + lr;
            const float s_r   = (n < 2) ? s0 : s1;
            const float sq2s  = (n < 2) ? sq2s0 : sq2s1;
            const float scale = (n < 2) ? sc0 : sc1;
            #pragma unroll
            for (int m = 0; m < 2; ++m) {
                const int tb4 = half * 32 + m * 16 + G * 4;
                #pragma unroll
                for (int j = 0; j < 4; ++j) {
                    const int t = tb4 + j;
                    const float proj = acc[m][n][j] * invn[p][t];
                    const float arg = fminf(fmaxf(proj * sq2s - s_r, -20.0f), 20.0f);
                    const float val = proj * proj * __expf(arg) * scale;
                    const short vb  = f2bf(val);
                    if (p == 0) { Qrm[t][f] = vb; }
                    else        { kfT[f][t] = vb; Krm[t][f] = vb; }
                }
            }
        }
    }
    {
        const int row = tid >> 2;
        const int c0  = (tid & 3) * 16;
        const short* vrow = qkvb + ((size_t)(b * T_ + t0 + row)) * THREEC
                          + 2 * EMBED + h * HD;
        bf16x8 v0 = *(const bf16x8*)&vrow[c0], v1 = *(const bf16x8*)&vrow[c0 + 8];
        #pragma unroll
        for (int j = 0; j < 8; ++j) {
            vT[c0 + j][row]     = v0[j];
            vT[c0 + 8 + j][row] = v1[j];
        }
    }
    __syncthreads();

    const int r0 = wave * 16;

    {
        const int row = tid >> 2;
        const int c0  = (tid & 3) * 16;
        short* dst = qf + ((size_t)bh * T_ + t0 + row) * NFEAT;
        *(bf16x8*)&dst[c0]     = *(const bf16x8*)&Qrm[row][c0];
        *(bf16x8*)&dst[c0 + 8] = *(const bf16x8*)&Qrm[row][c0 + 8];
    }
    bf16x8 aqq[2];
    aqq[0] = *(const bf16x8*)&Qrm[r0 + lr][kg8];
    aqq[1] = *(const bf16x8*)&Qrm[r0 + lr][32 + kg8];
    f32x4 accA[4] = {};
    #pragma unroll
    for (int n = 0; n < 4; ++n) {
        accA[n] = __builtin_amdgcn_mfma_f32_16x16x32_bf16(
            aqq[0], *(const bf16x8*)&Krm[n * 16 + lr][kg8], accA[n], 0, 0, 0);
        accA[n] = __builtin_amdgcn_mfma_f32_16x16x32_bf16(
            aqq[1], *(const bf16x8*)&Krm[n * 16 + lr][32 + kg8], accA[n], 0, 0, 0);
    }
    {
        float rsum[4] = {0.0f, 0.0f, 0.0f, 0.0f};
        #pragma unroll
        for (int n = 0; n < 4; ++n) {
            const int s = n * 16 + lr;
            #pragma unroll
            for (int j = 0; j < 4; ++j) {
                const int t = r0 + G * 4 + j;
                if (s <= t) rsum[j] += accA[n][j];
            }
        }
        #pragma unroll
        for (int j = 0; j < 4; ++j) {
            rsum[j] += __shfl_xor(rsum[j], 1, 64);
            rsum[j] += __shfl_xor(rsum[j], 2, 64);
            rsum[j] += __shfl_xor(rsum[j], 4, 64);
            rsum[j] += __shfl_xor(rsum[j], 8, 64);
        }
        if (lr == 0) {
            #pragma unroll
            for (int j = 0; j < 4; ++j) rs_l[r0 + G * 4 + j] = rsum[j];
        }
    }
    {
        bf16x8 a2[2];
        a2[0] = *(const bf16x8*)&kfT[wave * 16 + lr][kg8];
        a2[1] = *(const bf16x8*)&kfT[wave * 16 + lr][32 + kg8];
        f32x4 sa[4] = {};
        #pragma unroll
        for (int n = 0; n < 4; ++n) {
            sa[n] = __builtin_amdgcn_mfma_f32_16x16x32_bf16(
                a2[0], *(const bf16x8*)&vT[n * 16 + lr][kg8], sa[n], 0, 0, 0);
            sa[n] = __builtin_amdgcn_mfma_f32_16x16x32_bf16(
                a2[1], *(const bf16x8*)&vT[n * 16 + lr][32 + kg8], sa[n], 0, 0, 0);
        }
        short* basep = cKVb + (size_t)chunk * (NFEAT * HD);
        #pragma unroll
        for (int n = 0; n < 4; ++n) {
            bf16x4 o = { f2bf(sa[n][0]), f2bf(sa[n][1]),
                         f2bf(sa[n][2]), f2bf(sa[n][3]) };
            *(bf16x4*)&basep[(n * 16 + lr) * NFEAT + wave * 16 + G * 4] = o;
        }
    }
    {
        const int f  = tid >> 2;
        const int tq = tid & 3;
        float s = 0.0f;
        #pragma unroll
        for (int j = 0; j < 16; ++j) s += bf2f(kfT[f][tq * 16 + j]);
        s += __shfl_xor(s, 1, 64);
        s += __shfl_xor(s, 2, 64);
        if (tq == 0) cK[(size_t)chunk * NFEAT + f] = s;
    }
    __syncthreads();

    short (*At)[72] = oml;
    #pragma unroll
    for (int n = 0; n < 4; ++n) {
        const int s = n * 16 + lr;
        #pragma unroll
        for (int j = 0; j < 4; ++j) {
            const int t = r0 + G * 4 + j;
            At[t][s] = f2bf((s <= t) ? accA[n][j] : 0.0f);
        }
    }
    __syncthreads();

    {
        bf16x8 aa[2];
        aa[0] = *(const bf16x8*)&At[r0 + lr][kg8];
        aa[1] = *(const bf16x8*)&At[r0 + lr][32 + kg8];
        f32x4 a2[4] = {};
        #pragma unroll
        for (int n = 0; n < 4; ++n) {
            a2[n] = __builtin_amdgcn_mfma_f32_16x16x32_bf16(
                aa[0], *(const bf16x8*)&vT[n * 16 + lr][kg8], a2[n], 0, 0, 0);
            a2[n] = __builtin_amdgcn_mfma_f32_16x16x32_bf16(
                aa[1], *(const bf16x8*)&vT[n * 16 + lr][32 + kg8], a2[n], 0, 0, 0);
        }
        #pragma unroll
        for (int n = 0; n < 4; ++n) {
            const int d = n * 16 + lr;
            #pragma unroll
            for (int j = 0; j < 4; ++j) {
                const int t = r0 + G * 4 + j;
                At[t][d] = f2bf(a2[n][j]);   // own 16-row band: no cross-wave hazard
            }
        }
    }
    __syncthreads();
    {
        const int row = tid >> 2;
        const int c0  = (tid & 3) * 16;
        short* dst = ctxb + ((size_t)bh * T_ + t0 + row) * NFEAT;
        *(bf16x8*)&dst[c0]     = *(const bf16x8*)&At[row][c0];
        *(bf16x8*)&dst[c0 + 8] = *(const bf16x8*)&At[row][c0 + 8];
    }
    if (tid < 64) rs_g[(size_t)bh * T_ + t0 + tid] = rs_l[tid];
}

// ---------------------------------------------------------------------------
// Exclusive prefix over chunks, bf16 cKV (fp32 accumulators).
// ---------------------------------------------------------------------------
__global__ __launch_bounds__(256) void prefix_scan(
    short* __restrict__ cKVb, float* __restrict__ cK)
{
    const int bh  = blockIdx.x >> 2;
    const int sl  = blockIdx.x & 3;
    const int tid = threadIdx.x;
    short* base = cKVb + (size_t)bh * NC_ * (NFEAT * HD) + sl * 1024 + tid * 4;
    bf16x4 n0 = *(const bf16x4*)(base);
    bf16x4 n1 = *(const bf16x4*)(base + 4096);
    float pref[4] = {0.0f, 0.0f, 0.0f, 0.0f};
    for (int c = 0; c < NC_; ++c) {
        bf16x4 cur = n0;
        n0 = n1;
        if (c + 2 < NC_) n1 = *(const bf16x4*)(base + (size_t)(c + 2) * 4096);
        else { n1[0] = 0; n1[1] = 0; n1[2] = 0; n1[3] = 0; }
        bf16x4 o = { f2bf(pref[0]), f2bf(pref[1]), f2bf(pref[2]), f2bf(pref[3]) };
        *(bf16x4*)(base + (size_t)c * 4096) = o;
        pref[0] += bf2f(cur[0]); pref[1] += bf2f(cur[1]);
        pref[2] += bf2f(cur[2]); pref[3] += bf2f(cur[3]);
    }
    if (sl == 0 && tid < 64) {
        float* kb = cK + (size_t)bh * NC_ * NFEAT + tid;
        float m0 = kb[0];
        float m1 = kb[64];
        float p = 0.0f;
        for (int c = 0; c < NC_; ++c) {
            float cu = m0;
            m0 = m1;
            m1 = (c + 2 < NC_) ? kb[(size_t)(c + 2) * 64] : 0.0f;
            kb[(size_t)c * 64] = p;
            p += cu;
        }
    }
}

// ---------------------------------------------------------------------------
// Inter-chunk term + finalize; ctx staged through LDS coalesced.
// ---------------------------------------------------------------------------
__global__ __launch_bounds__(256) void inter_attn(
    const short* __restrict__ qf,
    const short* __restrict__ ctxb,
    const float* __restrict__ rs_g,
    const short* __restrict__ cKVp,
    const float* __restrict__ cKp_g,
    short* __restrict__ attnb)
{
    __shared__ short Q[64][72];
    __shared__ short Pp[64][72];
    __shared__ short Ct[64][72];
    __shared__ float cKp[64], rs[64], qkp_l[64];

    const int tid = threadIdx.x;
    const int chunk = blockIdx.x;
    const int bh = chunk >> 6, c = chunk & 63;
    const int b = bh >> 4, h = bh & 15;
    const int t0 = c * 64;

    {
        const int row = tid >> 2;
        const int c0  = (tid & 3) * 16;
        const short* qrow = qf   + ((size_t)bh * T_ + t0 + row) * NFEAT;
        const short* crow = ctxb + ((size_t)bh * T_ + t0 + row) * NFEAT;
        const short* prow = cKVp + (size_t)chunk * (NFEAT * HD) + row * NFEAT;
        *(bf16x8*)&Q[row][c0]      = *(const bf16x8*)&qrow[c0];
        *(bf16x8*)&Q[row][c0 + 8]  = *(const bf16x8*)&qrow[c0 + 8];
        *(bf16x8*)&Ct[row][c0]     = *(const bf16x8*)&crow[c0];
        *(bf16x8*)&Ct[row][c0 + 8] = *(const bf16x8*)&crow[c0 + 8];
        *(bf16x8*)&Pp[row][c0]     = *(const bf16x8*)&prow[c0];
        *(bf16x8*)&Pp[row][c0 + 8] = *(const bf16x8*)&prow[c0 + 8];
        if (tid < 64) {
            cKp[tid] = cKp_g[(size_t)chunk * NFEAT + tid];
            rs[tid]  = rs_g[(size_t)bh * T_ + t0 + tid];
        }
    }
    __syncthreads();

    {
        const int t  = tid >> 2;
        const int fq = (tid & 3) * 16;
        float s = 0.0f;
        #pragma unroll
        for (int j = 0; j < 16; ++j) s += bf2f(Q[t][fq + j]) * cKp[fq + j];
        s += __shfl_xor(s, 1, 64);
        s += __shfl_xor(s, 2, 64);
        if ((tid & 3) == 0) qkp_l[t] = s;
    }

    const int wave = tid >> 6;
    const int lane = tid & 63;
    const int lr = lane & 15;
    const int G  = lane >> 4;
    const int kg = G * 8;
    const int r0 = wave * 16;

    bf16x8 aq[2];
    aq[0] = *(const bf16x8*)&Q[r0 + lr][kg];
    aq[1] = *(const bf16x8*)&Q[r0 + lr][32 + kg];
    f32x4 acc[4] = {};
    #pragma unroll
    for (int n = 0; n < 4; ++n) {
        acc[n] = __builtin_amdgcn_mfma_f32_16x16x32_bf16(
            aq[0], *(const bf16x8*)&Pp[n * 16 + lr][kg], acc[n], 0, 0, 0);
        acc[n] = __builtin_amdgcn_mfma_f32_16x16x32_bf16(
            aq[1], *(const bf16x8*)&Pp[n * 16 + lr][32 + kg], acc[n], 0, 0, 0);
    }
    __syncthreads();

    float inv[4];
    #pragma unroll
    for (int j = 0; j < 4; ++j) {
        const int t = r0 + G * 4 + j;
        inv[j] = 1.0f / fmaxf(rs[t] + qkp_l[t], 1e-6f);
    }
    #pragma unroll
    for (int n = 0; n < 4; ++n) {
        const int d = n * 16 + lr;
        #pragma unroll
        for (int j = 0; j < 4; ++j) {
            const int t = r0 + G * 4 + j;
            const float ctx = bf2f(Ct[t][d]);
            attnb[((size_t)(b * T_ + t0 + t)) * EMBED + h * HD + d] =
                f2bf((ctx + acc[n][j]) * inv[j]);
        }
    }
}

// ---------------------------------------------------------------------------
extern "C" void kernel_launch(void* const* d_in, const int* in_sizes, int n_in,
                              void* d_out, int out_size, void* d_ws, size_t ws_size,
                              hipStream_t stream)
{
    const float* x     = (const float*)d_in[0];
    const float* w_qkv = (const float*)d_in[1];
    const float* b_qkv = (const float*)d_in[2];
    const float* w_out = (const float*)d_in[3];
    const float* b_out = (const float*)d_in[4];
    const float* omega = (const float*)d_in[5];
    const float* qn    = (const float*)d_in[6];
    const float* qw    = (const float*)d_in[7];
    float* out = (float*)d_out;

    short* xb    = (short*)d_ws;               //  8,388,608
    short* wqb   = xb    + 8388608;            //  3,145,728
    short* wob   = wqb   + 3145728;            //  1,048,576
    short* qkvb  = wob   + 1048576;            // 25,165,824
    short* attnb = qkvb  + 25165824;           //  8,388,608
    short* omgH  = attnb + 8388608;            //     65,536
    short* omgL  = omgH  + 65536;              //     65,536
    short* qfb   = omgL  + 65536;              //  8,388,608
    short* ctxb  = qfb   + 8388608;            //  8,388,608
    short* cKVb  = ctxb  + 8388608;            //  8,388,608
    float* cK    = (float*)(cKVb + 8388608);   //    131,072 floats
    float* rs_g  = cK + 131072;                //    131,072 floats

    const int M = B_ * T_;   // 8192

    prep_kernel<<<dim3((NV_ALL + 65536) / 256), 256, 0, stream>>>(
        x, w_qkv, w_out, omega, xb, wqb, wob, omgH, omgL);

    gemm_bf16<1><<<dim3((M / 128) * (THREEC / 128)), 256, 0, stream>>>(
        xb, wqb, b_qkv, nullptr, qkvb, M, THREEC, EMBED);
    feat_fused<<<dim3(BH_ * NC_), 256, 0, stream>>>(
        qkvb, omgH, omgL, qn, qw, qfb, ctxb, rs_g, cKVb, cK);
    prefix_scan<<<dim3(BH_ * 4), 256, 0, stream>>>(cKVb, cK);
    inter_attn<<<dim3(BH_ * NC_), 256, 0, stream>>>(
        qfb, ctxb, rs_g, cKVb, cK, attnb);
    gemm_bf16<0><<<dim3((EMBED / 128) * (M / 128)), 256, 0, stream>>>(
        attnb, wob, b_out, out, nullptr, M, EMBED, EMBED);
}